// Round 1
// baseline (1077.771 us; speedup 1.0000x reference)
//
#include <hip/hip_runtime.h>
#include <hip/hip_bf16.h>
#include <cstddef>

// ---------------------------------------------------------------------------
// DeformableTransformerDecoderLayer — round 1: correct f32 implementation.
// N=4, Lq=900, D=256, NH=8, dh=32, NL=4, NP=4, Len_in=17821, Dkv=384, Dffn=1024
// ---------------------------------------------------------------------------

constexpr int NB     = 4;
constexpr int LQ     = 900;
constexpr int DQ     = 256;
constexpr int DKV    = 384;
constexpr int DFFN   = 1024;
constexpr int NHD    = 8;
constexpr int DH     = 32;
constexpr int LEN_IN = 17821;

#define LN_EPS 1e-5f

// ---------------- elementwise add (float4) ----------------
__global__ void add_kernel(const float* __restrict__ a, const float* __restrict__ b,
                           float* __restrict__ c, int n4) {
    int i = blockIdx.x * blockDim.x + threadIdx.x;
    if (i < n4) {
        float4 va = reinterpret_cast<const float4*>(a)[i];
        float4 vb = reinterpret_cast<const float4*>(b)[i];
        reinterpret_cast<float4*>(c)[i] =
            make_float4(va.x + vb.x, va.y + vb.y, va.z + vb.z, va.w + vb.w);
    }
}

// ---------------- generic GEMM: C[M][N] = A[M][K] @ W[N][K]^T + bias ----------------
#define BM 64
#define BN 64
#define BK 16
__global__ __launch_bounds__(256) void gemm_atb(
        const float* __restrict__ A, const float* __restrict__ W,
        const float* __restrict__ bias, float* __restrict__ C,
        int M, int N, int K, int relu) {
    __shared__ float As[BK][BM];
    __shared__ float Bs[BK][BN];
    const int bm = blockIdx.y * BM;
    const int bn = blockIdx.x * BN;
    const int tid = threadIdx.x;
    const int tx = tid % 16, ty = tid / 16;
    float acc[4][4] = {};
    const int ktiles = K / BK;   // K is always a multiple of 16 here
    const int lr = tid / 4;          // 0..63
    const int lc = (tid % 4) * 4;    // 0,4,8,12
    for (int kt = 0; kt < ktiles; ++kt) {
        const int k0 = kt * BK;
        float4 va = make_float4(0.f, 0.f, 0.f, 0.f);
        float4 vb = make_float4(0.f, 0.f, 0.f, 0.f);
        const int arow = bm + lr;
        if (arow < M) va = *reinterpret_cast<const float4*>(&A[(size_t)arow * K + k0 + lc]);
        const int wrow = bn + lr;
        if (wrow < N) vb = *reinterpret_cast<const float4*>(&W[(size_t)wrow * K + k0 + lc]);
        As[lc + 0][lr] = va.x; As[lc + 1][lr] = va.y; As[lc + 2][lr] = va.z; As[lc + 3][lr] = va.w;
        Bs[lc + 0][lr] = vb.x; Bs[lc + 1][lr] = vb.y; Bs[lc + 2][lr] = vb.z; Bs[lc + 3][lr] = vb.w;
        __syncthreads();
        #pragma unroll
        for (int k = 0; k < BK; ++k) {
            float av[4], bv[4];
            #pragma unroll
            for (int i = 0; i < 4; ++i) av[i] = As[k][ty * 4 + i];
            #pragma unroll
            for (int j = 0; j < 4; ++j) bv[j] = Bs[k][tx * 4 + j];
            #pragma unroll
            for (int i = 0; i < 4; ++i)
                #pragma unroll
                for (int j = 0; j < 4; ++j)
                    acc[i][j] += av[i] * bv[j];
        }
        __syncthreads();
    }
    #pragma unroll
    for (int i = 0; i < 4; ++i) {
        const int row = bm + ty * 4 + i;
        if (row >= M) continue;
        #pragma unroll
        for (int j = 0; j < 4; ++j) {
            const int col = bn + tx * 4 + j;
            if (col >= N) continue;
            float v = acc[i][j] + bias[col];
            if (relu) v = fmaxf(v, 0.f);
            C[(size_t)row * N + col] = v;
        }
    }
}

// ---------------- flash-style MHA: one query per thread ----------------
#define TK 32
__global__ __launch_bounds__(256) void attn_kernel(
        const float* __restrict__ q_proj, const float* __restrict__ k_proj,
        const float* __restrict__ v_proj, float* __restrict__ o_out) {
    const int n = blockIdx.z, h = blockIdx.y;
    const int q = blockIdx.x * 256 + threadIdx.x;
    const bool active = q < LQ;
    __shared__ float Ks[TK][DH];
    __shared__ float Vs[TK][DH];
    float qv[DH], o[DH];
    float m = -1e30f, l = 0.f;
    const float scale = 0.17677669529663687f;  // 1/sqrt(32)
    if (active) {
        const float* qp = &q_proj[((size_t)(n * LQ + q)) * DQ + h * DH];
        #pragma unroll
        for (int d = 0; d < DH; ++d) { qv[d] = qp[d] * scale; o[d] = 0.f; }
    }
    const int ntiles = (LQ + TK - 1) / TK;
    for (int t = 0; t < ntiles; ++t) {
        const int kbase = t * TK;
        {
            const int idx = threadIdx.x;   // 0..255 -> 32 rows x 8 float4
            const int r = idx / 8;
            const int c = (idx % 8) * 4;
            const int key = kbase + r;
            float4 kv4 = make_float4(0.f, 0.f, 0.f, 0.f);
            float4 vv4 = make_float4(0.f, 0.f, 0.f, 0.f);
            if (key < LQ) {
                kv4 = *reinterpret_cast<const float4*>(&k_proj[((size_t)(n * LQ + key)) * DQ + h * DH + c]);
                vv4 = *reinterpret_cast<const float4*>(&v_proj[((size_t)(n * LQ + key)) * DQ + h * DH + c]);
            }
            *reinterpret_cast<float4*>(&Ks[r][c]) = kv4;
            *reinterpret_cast<float4*>(&Vs[r][c]) = vv4;
        }
        __syncthreads();
        if (active) {
            float s[TK];
            #pragma unroll
            for (int kk = 0; kk < TK; ++kk) {
                float acc = 0.f;
                #pragma unroll
                for (int d = 0; d < DH; ++d) acc += qv[d] * Ks[kk][d];
                s[kk] = ((kbase + kk) < LQ) ? acc : -1e30f;
            }
            float tmax = -1e30f;
            #pragma unroll
            for (int kk = 0; kk < TK; ++kk) tmax = fmaxf(tmax, s[kk]);
            const float mnew = fmaxf(m, tmax);
            const float corr = __expf(m - mnew);
            l *= corr;
            #pragma unroll
            for (int d = 0; d < DH; ++d) o[d] *= corr;
            #pragma unroll
            for (int kk = 0; kk < TK; ++kk) {
                const float p = __expf(s[kk] - mnew);
                l += p;
                #pragma unroll
                for (int d = 0; d < DH; ++d) o[d] += p * Vs[kk][d];
            }
            m = mnew;
        }
        __syncthreads();
    }
    if (active) {
        const float inv = 1.f / l;
        float* op = &o_out[((size_t)(n * LQ + q)) * DQ + h * DH];
        #pragma unroll
        for (int d = 0; d < DH; ++d) op[d] = o[d] * inv;
    }
}

// ---------------- fused residual + LayerNorm: out = LN(a+b)*g+beta ----------------
__global__ __launch_bounds__(64) void ln_kernel(
        const float* __restrict__ a, const float* __restrict__ b,
        const float* __restrict__ g, const float* __restrict__ beta,
        float* __restrict__ out) {
    const int row = blockIdx.x;
    const int lane = threadIdx.x;
    const float* ap = &a[(size_t)row * DQ];
    const float* bp = &b[(size_t)row * DQ];
    float x[4];
    float s = 0.f;
    #pragma unroll
    for (int i = 0; i < 4; ++i) { x[i] = ap[lane + i * 64] + bp[lane + i * 64]; s += x[i]; }
    #pragma unroll
    for (int off = 32; off > 0; off >>= 1) s += __shfl_xor(s, off);
    const float mean = s * (1.f / DQ);
    float v = 0.f;
    #pragma unroll
    for (int i = 0; i < 4; ++i) { const float d = x[i] - mean; v += d * d; }
    #pragma unroll
    for (int off = 32; off > 0; off >>= 1) v += __shfl_xor(v, off);
    const float rstd = rsqrtf(v * (1.f / DQ) + LN_EPS);
    #pragma unroll
    for (int i = 0; i < 4; ++i) {
        const int c = lane + i * 64;
        out[(size_t)row * DQ + c] = (x[i] - mean) * rstd * g[c] + beta[c];
    }
}

// ---------------- softmax over 16 (NL*NP) per (n,q,h) ----------------
__global__ void softmax16_kernel(const float* __restrict__ in, float* __restrict__ out, int total) {
    const int i = blockIdx.x * blockDim.x + threadIdx.x;
    if (i >= total) return;
    const float* p = &in[(size_t)i * 16];
    float mx = -1e30f;
    float e[16];
    #pragma unroll
    for (int j = 0; j < 16; ++j) mx = fmaxf(mx, p[j]);
    float sum = 0.f;
    #pragma unroll
    for (int j = 0; j < 16; ++j) { e[j] = __expf(p[j] - mx); sum += e[j]; }
    const float inv = 1.f / sum;
    #pragma unroll
    for (int j = 0; j < 16; ++j) out[(size_t)i * 16 + j] = e[j] * inv;
}

// ---------------- deformable sampling + weighted aggregation ----------------
// block = (n,q); thread = (h = tid/32, d = tid%32)
__global__ __launch_bounds__(256) void deform_kernel(
        const float* __restrict__ value,     // (N, Len, NH, DH)
        const float* __restrict__ ref_pts,   // (N, Lq, NL, 2)
        const float* __restrict__ off,       // (N, Lq, NH, NL, NP, 2)
        const float* __restrict__ aw,        // (N, Lq, NH, NL*NP)
        float* __restrict__ out) {           // (N, Lq, NH, DH)
    const int nq = blockIdx.x;
    const int n = nq / LQ, q = nq % LQ;
    const int h = threadIdx.x / DH, d = threadIdx.x % DH;
    const int Hs[4] = {100, 50, 25, 13};
    const int Ws[4] = {134, 67, 34, 17};
    const int LS[4] = {0, 13400, 16750, 17600};
    const float* refp = &ref_pts[((size_t)(n * LQ + q)) * 8];           // NL*2
    const float* offp = &off[((size_t)((n * LQ + q) * NHD + h)) * 32];  // NL*NP*2
    const float* awp  = &aw[((size_t)((n * LQ + q) * NHD + h)) * 16];
    const float* vb   = &value[(size_t)n * LEN_IN * DQ + h * DH + d];
    float acc = 0.f;
    #pragma unroll
    for (int l = 0; l < 4; ++l) {
        const float Wl = (float)Ws[l], Hl = (float)Hs[l];
        const float rx = refp[l * 2 + 0], ry = refp[l * 2 + 1];
        const int Wi = Ws[l], Hi = Hs[l], base = LS[l];
        #pragma unroll
        for (int p = 0; p < 4; ++p) {
            const float ox = offp[(l * 4 + p) * 2 + 0];
            const float oy = offp[(l * 4 + p) * 2 + 1];
            const float gx = (rx + ox / Wl) * Wl - 0.5f;
            const float gy = (ry + oy / Hl) * Hl - 0.5f;
            const float x0f = floorf(gx), y0f = floorf(gy);
            const int x0 = (int)x0f, y0 = (int)y0f;
            const int x1 = x0 + 1, y1 = y0 + 1;
            const float wx1 = gx - x0f, wx0 = 1.f - wx1;
            const float wy1 = gy - y0f, wy0 = 1.f - wy1;
            float sample = 0.f;
            if (x0 >= 0 && x0 < Wi && y0 >= 0 && y0 < Hi)
                sample += wx0 * wy0 * vb[(size_t)(base + y0 * Wi + x0) * DQ];
            if (x1 >= 0 && x1 < Wi && y0 >= 0 && y0 < Hi)
                sample += wx1 * wy0 * vb[(size_t)(base + y0 * Wi + x1) * DQ];
            if (x0 >= 0 && x0 < Wi && y1 >= 0 && y1 < Hi)
                sample += wx0 * wy1 * vb[(size_t)(base + y1 * Wi + x0) * DQ];
            if (x1 >= 0 && x1 < Wi && y1 >= 0 && y1 < Hi)
                sample += wx1 * wy1 * vb[(size_t)(base + y1 * Wi + x1) * DQ];
            acc += awp[l * 4 + p] * sample;
        }
    }
    out[((size_t)(n * LQ + q)) * DQ + h * DH + d] = acc;
}

// ---------------------------------------------------------------------------
static inline void gemm_launch(const float* A, const float* W, const float* bias, float* C,
                               int M, int N, int K, int relu, hipStream_t stream) {
    dim3 grid((N + BN - 1) / BN, (M + BM - 1) / BM);
    hipLaunchKernelGGL(gemm_atb, grid, dim3(256), 0, stream, A, W, bias, C, M, N, K, relu);
}

extern "C" void kernel_launch(void* const* d_in, const int* in_sizes, int n_in,
                              void* d_out, int out_size, void* d_ws, size_t ws_size,
                              hipStream_t stream) {
    const float* queries   = (const float*)d_in[0];
    const float* features  = (const float*)d_in[1];
    const float* ref_pts   = (const float*)d_in[2];
    const float* q_pos     = (const float*)d_in[3];
    const float* in_proj_w = (const float*)d_in[6];
    const float* in_proj_b = (const float*)d_in[7];
    const float* mha_out_w = (const float*)d_in[8];
    const float* mha_out_b = (const float*)d_in[9];
    const float* value_proj_w = (const float*)d_in[10];
    const float* value_proj_b = (const float*)d_in[11];
    const float* samp_off_w = (const float*)d_in[12];
    const float* samp_off_b = (const float*)d_in[13];
    const float* attn_w_w  = (const float*)d_in[14];
    const float* attn_w_b  = (const float*)d_in[15];
    const float* out_proj_w = (const float*)d_in[16];
    const float* out_proj_b = (const float*)d_in[17];
    const float* ffn_w1    = (const float*)d_in[18];
    const float* ffn_b1    = (const float*)d_in[19];
    const float* ffn_w2    = (const float*)d_in[20];
    const float* ffn_b2    = (const float*)d_in[21];
    const float* ln1_g     = (const float*)d_in[22];
    const float* ln1_b     = (const float*)d_in[23];
    const float* ln2_g     = (const float*)d_in[24];
    const float* ln2_b     = (const float*)d_in[25];
    const float* ln3_g     = (const float*)d_in[26];
    const float* ln3_b     = (const float*)d_in[27];

    float* ws = (float*)d_ws;
    const size_t NLqD = (size_t)NB * LQ * DQ;        // 921600
    float* qk     = ws + 0 * NLqD;
    float* q_proj = ws + 1 * NLqD;
    float* k_proj = ws + 2 * NLqD;
    float* v_proj = ws + 3 * NLqD;
    float* attno  = ws + 4 * NLqD;
    float* sa     = ws + 5 * NLqD;
    float* x1     = ws + 6 * NLqD;
    float* qpe    = ws + 7 * NLqD;
    float* offb   = ws + 8 * NLqD;
    float* dout   = ws + 9 * NLqD;
    float* ca     = ws + 10 * NLqD;
    float* x2     = ws + 11 * NLqD;
    float* ffnout = ws + 12 * NLqD;
    float* awlog  = ws + 13 * NLqD;                  // N*Lq*128 = 460800
    float* awbuf  = awlog + (size_t)NB * LQ * 128;   // 460800 more (fits slot 13)
    float* ffnh   = ws + 14 * NLqD;                  // N*Lq*1024 = 4 slots
    float* value  = ws + 18 * NLqD;                  // N*Len*256 = 18248704 floats

    const int M = NB * LQ;                 // 3600
    const int n4 = (int)(NLqD / 4);        // 230400

    // 1. qk = queries + q_pos
    hipLaunchKernelGGL(add_kernel, dim3((n4 + 255) / 256), dim3(256), 0, stream,
                       queries, q_pos, qk, n4);
    // 2. q/k/v projections (q,k from qk; v from queries)
    gemm_launch(qk, in_proj_w,            in_proj_b,       q_proj, M, DQ, DQ, 0, stream);
    gemm_launch(qk, in_proj_w + 256 * DQ, in_proj_b + 256, k_proj, M, DQ, DQ, 0, stream);
    gemm_launch(queries, in_proj_w + 512 * DQ, in_proj_b + 512, v_proj, M, DQ, DQ, 0, stream);
    // 3. self-attention
    hipLaunchKernelGGL(attn_kernel, dim3((LQ + 255) / 256, NHD, NB), dim3(256), 0, stream,
                       q_proj, k_proj, v_proj, attno);
    // 4. mha out projection
    gemm_launch(attno, mha_out_w, mha_out_b, sa, M, DQ, DQ, 0, stream);
    // 5. x1 = LN(queries + sa)
    hipLaunchKernelGGL(ln_kernel, dim3(M), dim3(64), 0, stream, queries, sa, ln1_g, ln1_b, x1);
    // 6. qpe = x1 + q_pos
    hipLaunchKernelGGL(add_kernel, dim3((n4 + 255) / 256), dim3(256), 0, stream,
                       x1, q_pos, qpe, n4);
    // 7. value projection over features
    gemm_launch(features, value_proj_w, value_proj_b, value, NB * LEN_IN, DQ, DKV, 0, stream);
    // 8. sampling offsets
    gemm_launch(qpe, samp_off_w, samp_off_b, offb, M, DQ, DQ, 0, stream);
    // 9. attention weights + softmax16
    gemm_launch(qpe, attn_w_w, attn_w_b, awlog, M, 128, DQ, 0, stream);
    {
        const int total = NB * LQ * NHD;  // 28800
        hipLaunchKernelGGL(softmax16_kernel, dim3((total + 255) / 256), dim3(256), 0, stream,
                           awlog, awbuf, total);
    }
    // 10. deformable sampling
    hipLaunchKernelGGL(deform_kernel, dim3(NB * LQ), dim3(256), 0, stream,
                       value, ref_pts, offb, awbuf, dout);
    // 11. cross-attention out projection
    gemm_launch(dout, out_proj_w, out_proj_b, ca, M, DQ, DQ, 0, stream);
    // 12. x2 = LN(x1 + ca)
    hipLaunchKernelGGL(ln_kernel, dim3(M), dim3(64), 0, stream, x1, ca, ln2_g, ln2_b, x2);
    // 13. ffn
    gemm_launch(x2, ffn_w1, ffn_b1, ffnh, M, DFFN, DQ, 1, stream);
    gemm_launch(ffnh, ffn_w2, ffn_b2, ffnout, M, DQ, DFFN, 0, stream);
    // 14. out = LN(x2 + ffn)
    hipLaunchKernelGGL(ln_kernel, dim3(M), dim3(64), 0, stream, x2, ffnout, ln3_g, ln3_b, (float*)d_out);
}

// Round 2
// 562.213 us; speedup vs baseline: 1.9170x; 1.9170x over previous
//
#include <hip/hip_runtime.h>
#include <hip/hip_bf16.h>
#include <cstddef>

// ---------------------------------------------------------------------------
// DeformableTransformerDecoderLayer — round 2:
//   * all GEMMs -> bf16 MFMA (f32 accumulate), 64^2 / 128^2 tiles
//   * self-attention -> split-K flash (10 splits) + combine
// N=4, Lq=900, D=256, NH=8, dh=32, NL=4, NP=4, Len_in=17821, Dkv=384, Dffn=1024
// ---------------------------------------------------------------------------

constexpr int NB     = 4;
constexpr int LQ     = 900;
constexpr int DQ     = 256;
constexpr int DKV    = 384;
constexpr int DFFN   = 1024;
constexpr int NHD    = 8;
constexpr int DH     = 32;
constexpr int LEN_IN = 17821;

#define LN_EPS 1e-5f

typedef short  bf16x8 __attribute__((ext_vector_type(8)));
typedef float  f32x4  __attribute__((ext_vector_type(4)));

__device__ inline unsigned short f2bf(float f) {
    union { float f; unsigned int u; } v; v.f = f;
    unsigned int u = v.u;
    u += 0x7fffu + ((u >> 16) & 1u);     // round-to-nearest-even
    return (unsigned short)(u >> 16);
}

// ---------------- elementwise add (float4) ----------------
__global__ void add_kernel(const float* __restrict__ a, const float* __restrict__ b,
                           float* __restrict__ c, int n4) {
    int i = blockIdx.x * blockDim.x + threadIdx.x;
    if (i < n4) {
        float4 va = reinterpret_cast<const float4*>(a)[i];
        float4 vb = reinterpret_cast<const float4*>(b)[i];
        reinterpret_cast<float4*>(c)[i] =
            make_float4(va.x + vb.x, va.y + vb.y, va.z + vb.z, va.w + vb.w);
    }
}

// ---------------- bf16 MFMA GEMM: C[M][N] = A[M][K] @ W[N][K]^T + bias ------
// A,W are f32 in HBM; converted to bf16 during LDS staging. f32 accumulate.
// 256 threads = 4 waves. Wave grid (BM/WM) x (BN/WN) must equal 4.
template<int BM, int BN, int WM, int WN>
__global__ __launch_bounds__(256) void gemm_mfma(
        const float* __restrict__ A, const float* __restrict__ W,
        const float* __restrict__ bias, float* __restrict__ C,
        int M, int N, int K, int relu) {
    constexpr int BK  = 32;
    constexpr int PAD = 40;                    // shorts per LDS row (80B: conflict-free-ish)
    __shared__ alignas(16) unsigned short As[BM][PAD];
    __shared__ alignas(16) unsigned short Bs[BN][PAD];
    const int bm = blockIdx.y * BM;
    const int bn = blockIdx.x * BN;
    const int tid  = threadIdx.x;
    const int wid  = tid >> 6;
    const int lane = tid & 63;
    constexpr int NWC = BN / WN;
    const int wr = wid / NWC, wc = wid % NWC;
    constexpr int MR = WM / 16, NR = WN / 16;

    f32x4 acc[MR][NR];
    #pragma unroll
    for (int i = 0; i < MR; ++i)
        #pragma unroll
        for (int j = 0; j < NR; ++j)
            acc[i][j] = (f32x4){0.f, 0.f, 0.f, 0.f};

    constexpr int SEG = (BM * BK) / 256;       // floats staged per thread per matrix
    constexpr int TPR = BK / SEG;              // threads per row
    const int srow = tid / TPR;
    const int scol = (tid % TPR) * SEG;

    const int kb  = (lane >> 4) * 8;           // k-base within the 32-wide tile
    const int r16 = lane & 15;

    for (int k0 = 0; k0 < K; k0 += BK) {
        // ---- stage A tile ----
        {
            float tmp[SEG];
            const int ga = bm + srow;
            if (ga < M) {
                #pragma unroll
                for (int i = 0; i < SEG; i += 4)
                    *reinterpret_cast<float4*>(&tmp[i]) =
                        *reinterpret_cast<const float4*>(&A[(size_t)ga * K + k0 + scol + i]);
            } else {
                #pragma unroll
                for (int i = 0; i < SEG; ++i) tmp[i] = 0.f;
            }
            #pragma unroll
            for (int seg8 = 0; seg8 < SEG / 8; ++seg8) {
                unsigned short h[8];
                #pragma unroll
                for (int i = 0; i < 8; ++i) h[i] = f2bf(tmp[seg8 * 8 + i]);
                *reinterpret_cast<bf16x8*>(&As[srow][scol + seg8 * 8]) =
                    *reinterpret_cast<bf16x8*>(h);
            }
        }
        // ---- stage B (weight) tile ----
        {
            float tmp[SEG];
            const int gw = bn + srow;
            if (gw < N) {
                #pragma unroll
                for (int i = 0; i < SEG; i += 4)
                    *reinterpret_cast<float4*>(&tmp[i]) =
                        *reinterpret_cast<const float4*>(&W[(size_t)gw * K + k0 + scol + i]);
            } else {
                #pragma unroll
                for (int i = 0; i < SEG; ++i) tmp[i] = 0.f;
            }
            #pragma unroll
            for (int seg8 = 0; seg8 < SEG / 8; ++seg8) {
                unsigned short h[8];
                #pragma unroll
                for (int i = 0; i < 8; ++i) h[i] = f2bf(tmp[seg8 * 8 + i]);
                *reinterpret_cast<bf16x8*>(&Bs[srow][scol + seg8 * 8]) =
                    *reinterpret_cast<bf16x8*>(h);
            }
        }
        __syncthreads();
        // ---- fragments + MFMA ----
        bf16x8 af[MR], bfr[NR];
        #pragma unroll
        for (int i = 0; i < MR; ++i)
            af[i] = *reinterpret_cast<const bf16x8*>(&As[wr * WM + i * 16 + r16][kb]);
        #pragma unroll
        for (int j = 0; j < NR; ++j)
            bfr[j] = *reinterpret_cast<const bf16x8*>(&Bs[wc * WN + j * 16 + r16][kb]);
        #pragma unroll
        for (int i = 0; i < MR; ++i)
            #pragma unroll
            for (int j = 0; j < NR; ++j)
                acc[i][j] = __builtin_amdgcn_mfma_f32_16x16x32_bf16(af[i], bfr[j], acc[i][j], 0, 0, 0);
        __syncthreads();
    }
    // ---- epilogue: D layout col = lane&15, row = (lane>>4)*4 + r ----
    #pragma unroll
    for (int i = 0; i < MR; ++i) {
        #pragma unroll
        for (int j = 0; j < NR; ++j) {
            const int col   = bn + wc * WN + j * 16 + r16;
            const int rbase = bm + wr * WM + i * 16 + (lane >> 4) * 4;
            const float bv = bias[col];
            #pragma unroll
            for (int r = 0; r < 4; ++r) {
                const int row = rbase + r;
                if (row < M) {
                    float v = acc[i][j][r] + bv;
                    if (relu) v = fmaxf(v, 0.f);
                    C[(size_t)row * N + col] = v;
                }
            }
        }
    }
}

// ---------------- split-K flash MHA ----------------
#define SPLITS 10
#define KPS    90      // keys per split (10*90 = 900)
#define TK     32
__global__ __launch_bounds__(256) void attn_split_kernel(
        const float* __restrict__ q_proj, const float* __restrict__ k_proj,
        const float* __restrict__ v_proj,
        float* __restrict__ pO, float* __restrict__ pM, float* __restrict__ pL) {
    const int n = blockIdx.z / SPLITS, s = blockIdx.z % SPLITS;
    const int h = blockIdx.y;
    const int q = blockIdx.x * 256 + threadIdx.x;
    const bool active = q < LQ;
    const int kbegin = s * KPS;
    __shared__ float Ks[TK][DH];
    __shared__ float Vs[TK][DH];
    float qv[DH], o[DH];
    float m = -1e30f, l = 0.f;
    const float scale = 0.17677669529663687f;  // 1/sqrt(32)
    if (active) {
        const float* qp = &q_proj[((size_t)(n * LQ + q)) * DQ + h * DH];
        #pragma unroll
        for (int d = 0; d < DH; ++d) { qv[d] = qp[d] * scale; o[d] = 0.f; }
    }
    for (int t = 0; t < (KPS + TK - 1) / TK; ++t) {
        const int kbase = t * TK;
        {
            const int idx = threadIdx.x;   // 32 rows x 8 float4
            const int r = idx / 8;
            const int c = (idx % 8) * 4;
            float4 kv4 = make_float4(0.f, 0.f, 0.f, 0.f);
            float4 vv4 = make_float4(0.f, 0.f, 0.f, 0.f);
            if (kbase + r < KPS) {
                const size_t base = ((size_t)(n * LQ + kbegin + kbase + r)) * DQ + h * DH + c;
                kv4 = *reinterpret_cast<const float4*>(&k_proj[base]);
                vv4 = *reinterpret_cast<const float4*>(&v_proj[base]);
            }
            *reinterpret_cast<float4*>(&Ks[r][c]) = kv4;
            *reinterpret_cast<float4*>(&Vs[r][c]) = vv4;
        }
        __syncthreads();
        if (active) {
            float sc[TK];
            #pragma unroll
            for (int kk = 0; kk < TK; ++kk) {
                float acc = 0.f;
                #pragma unroll
                for (int d = 0; d < DH; ++d) acc += qv[d] * Ks[kk][d];
                sc[kk] = (kbase + kk < KPS) ? acc : -1e30f;
            }
            float tmax = -1e30f;
            #pragma unroll
            for (int kk = 0; kk < TK; ++kk) tmax = fmaxf(tmax, sc[kk]);
            const float mnew = fmaxf(m, tmax);
            const float corr = __expf(m - mnew);
            l *= corr;
            #pragma unroll
            for (int d = 0; d < DH; ++d) o[d] *= corr;
            #pragma unroll
            for (int kk = 0; kk < TK; ++kk) {
                const float p = __expf(sc[kk] - mnew);
                l += p;
                #pragma unroll
                for (int d = 0; d < DH; ++d) o[d] += p * Vs[kk][d];
            }
            m = mnew;
        }
        __syncthreads();
    }
    if (active) {
        const size_t idx = ((size_t)((n * SPLITS + s) * LQ + q)) * NHD + h;
        float* op = &pO[idx * DH];
        #pragma unroll
        for (int d = 0; d < DH; ++d) op[d] = o[d];
        pM[idx] = m;
        pL[idx] = l;
    }
}

__global__ __launch_bounds__(256) void attn_combine_kernel(
        const float* __restrict__ pO, const float* __restrict__ pM,
        const float* __restrict__ pL, float* __restrict__ attno) {
    const int nq = blockIdx.x;
    const int n = nq / LQ, q = nq % LQ;
    const int h = threadIdx.x >> 5, d = threadIdx.x & 31;
    float ms[SPLITS], ls[SPLITS];
    float m = -1e30f;
    #pragma unroll
    for (int s = 0; s < SPLITS; ++s) {
        const size_t idx = ((size_t)((n * SPLITS + s) * LQ + q)) * NHD + h;
        ms[s] = pM[idx]; ls[s] = pL[idx];
        m = fmaxf(m, ms[s]);
    }
    float l = 0.f, o = 0.f;
    #pragma unroll
    for (int s = 0; s < SPLITS; ++s) {
        const size_t idx = ((size_t)((n * SPLITS + s) * LQ + q)) * NHD + h;
        const float w = __expf(ms[s] - m);
        l += w * ls[s];
        o += w * pO[idx * DH + d];
    }
    attno[((size_t)(n * LQ + q)) * DQ + h * DH + d] = o / l;
}

// ---------------- fused residual + LayerNorm ----------------
__global__ __launch_bounds__(64) void ln_kernel(
        const float* __restrict__ a, const float* __restrict__ b,
        const float* __restrict__ g, const float* __restrict__ beta,
        float* __restrict__ out) {
    const int row = blockIdx.x;
    const int lane = threadIdx.x;
    const float* ap = &a[(size_t)row * DQ];
    const float* bp = &b[(size_t)row * DQ];
    float x[4];
    float s = 0.f;
    #pragma unroll
    for (int i = 0; i < 4; ++i) { x[i] = ap[lane + i * 64] + bp[lane + i * 64]; s += x[i]; }
    #pragma unroll
    for (int off = 32; off > 0; off >>= 1) s += __shfl_xor(s, off);
    const float mean = s * (1.f / DQ);
    float v = 0.f;
    #pragma unroll
    for (int i = 0; i < 4; ++i) { const float d = x[i] - mean; v += d * d; }
    #pragma unroll
    for (int off = 32; off > 0; off >>= 1) v += __shfl_xor(v, off);
    const float rstd = rsqrtf(v * (1.f / DQ) + LN_EPS);
    #pragma unroll
    for (int i = 0; i < 4; ++i) {
        const int c = lane + i * 64;
        out[(size_t)row * DQ + c] = (x[i] - mean) * rstd * g[c] + beta[c];
    }
}

// ---------------- softmax over 16 per (n,q,h) ----------------
__global__ void softmax16_kernel(const float* __restrict__ in, float* __restrict__ out, int total) {
    const int i = blockIdx.x * blockDim.x + threadIdx.x;
    if (i >= total) return;
    const float* p = &in[(size_t)i * 16];
    float mx = -1e30f;
    float e[16];
    #pragma unroll
    for (int j = 0; j < 16; ++j) mx = fmaxf(mx, p[j]);
    float sum = 0.f;
    #pragma unroll
    for (int j = 0; j < 16; ++j) { e[j] = __expf(p[j] - mx); sum += e[j]; }
    const float inv = 1.f / sum;
    #pragma unroll
    for (int j = 0; j < 16; ++j) out[(size_t)i * 16 + j] = e[j] * inv;
}

// ---------------- deformable sampling + weighted aggregation ----------------
__global__ __launch_bounds__(256) void deform_kernel(
        const float* __restrict__ value,     // (N, Len, NH, DH)
        const float* __restrict__ ref_pts,   // (N, Lq, NL, 2)
        const float* __restrict__ off,       // (N, Lq, NH, NL, NP, 2)
        const float* __restrict__ aw,        // (N, Lq, NH, NL*NP)
        float* __restrict__ out) {           // (N, Lq, NH, DH)
    const int nq = blockIdx.x;
    const int n = nq / LQ, q = nq % LQ;
    const int h = threadIdx.x / DH, d = threadIdx.x % DH;
    const int Hs[4] = {100, 50, 25, 13};
    const int Ws[4] = {134, 67, 34, 17};
    const int LS[4] = {0, 13400, 16750, 17600};
    const float* refp = &ref_pts[((size_t)(n * LQ + q)) * 8];
    const float* offp = &off[((size_t)((n * LQ + q) * NHD + h)) * 32];
    const float* awp  = &aw[((size_t)((n * LQ + q) * NHD + h)) * 16];
    const float* vb   = &value[(size_t)n * LEN_IN * DQ + h * DH + d];
    float acc = 0.f;
    #pragma unroll
    for (int l = 0; l < 4; ++l) {
        const float Wl = (float)Ws[l], Hl = (float)Hs[l];
        const float rx = refp[l * 2 + 0], ry = refp[l * 2 + 1];
        const int Wi = Ws[l], Hi = Hs[l], base = LS[l];
        #pragma unroll
        for (int p = 0; p < 4; ++p) {
            const float ox = offp[(l * 4 + p) * 2 + 0];
            const float oy = offp[(l * 4 + p) * 2 + 1];
            const float gx = (rx + ox / Wl) * Wl - 0.5f;
            const float gy = (ry + oy / Hl) * Hl - 0.5f;
            const float x0f = floorf(gx), y0f = floorf(gy);
            const int x0 = (int)x0f, y0 = (int)y0f;
            const int x1 = x0 + 1, y1 = y0 + 1;
            const float wx1 = gx - x0f, wx0 = 1.f - wx1;
            const float wy1 = gy - y0f, wy0 = 1.f - wy1;
            float sample = 0.f;
            if (x0 >= 0 && x0 < Wi && y0 >= 0 && y0 < Hi)
                sample += wx0 * wy0 * vb[(size_t)(base + y0 * Wi + x0) * DQ];
            if (x1 >= 0 && x1 < Wi && y0 >= 0 && y0 < Hi)
                sample += wx1 * wy0 * vb[(size_t)(base + y0 * Wi + x1) * DQ];
            if (x0 >= 0 && x0 < Wi && y1 >= 0 && y1 < Hi)
                sample += wx0 * wy1 * vb[(size_t)(base + y1 * Wi + x0) * DQ];
            if (x1 >= 0 && x1 < Wi && y1 >= 0 && y1 < Hi)
                sample += wx1 * wy1 * vb[(size_t)(base + y1 * Wi + x1) * DQ];
            acc += awp[l * 4 + p] * sample;
        }
    }
    out[((size_t)(n * LQ + q)) * DQ + h * DH + d] = acc;
}

// ---------------------------------------------------------------------------
static inline void gemm64(const float* A, const float* W, const float* bias, float* C,
                          int M, int N, int K, int relu, hipStream_t stream) {
    dim3 grid(N / 64, (M + 63) / 64);
    hipLaunchKernelGGL((gemm_mfma<64, 64, 32, 32>), grid, dim3(256), 0, stream,
                       A, W, bias, C, M, N, K, relu);
}
static inline void gemm128(const float* A, const float* W, const float* bias, float* C,
                           int M, int N, int K, int relu, hipStream_t stream) {
    dim3 grid(N / 128, (M + 127) / 128);
    hipLaunchKernelGGL((gemm_mfma<128, 128, 64, 64>), grid, dim3(256), 0, stream,
                       A, W, bias, C, M, N, K, relu);
}

extern "C" void kernel_launch(void* const* d_in, const int* in_sizes, int n_in,
                              void* d_out, int out_size, void* d_ws, size_t ws_size,
                              hipStream_t stream) {
    const float* queries   = (const float*)d_in[0];
    const float* features  = (const float*)d_in[1];
    const float* ref_pts   = (const float*)d_in[2];
    const float* q_pos     = (const float*)d_in[3];
    const float* in_proj_w = (const float*)d_in[6];
    const float* in_proj_b = (const float*)d_in[7];
    const float* mha_out_w = (const float*)d_in[8];
    const float* mha_out_b = (const float*)d_in[9];
    const float* value_proj_w = (const float*)d_in[10];
    const float* value_proj_b = (const float*)d_in[11];
    const float* samp_off_w = (const float*)d_in[12];
    const float* samp_off_b = (const float*)d_in[13];
    const float* attn_w_w  = (const float*)d_in[14];
    const float* attn_w_b  = (const float*)d_in[15];
    const float* out_proj_w = (const float*)d_in[16];
    const float* out_proj_b = (const float*)d_in[17];
    const float* ffn_w1    = (const float*)d_in[18];
    const float* ffn_b1    = (const float*)d_in[19];
    const float* ffn_w2    = (const float*)d_in[20];
    const float* ffn_b2    = (const float*)d_in[21];
    const float* ln1_g     = (const float*)d_in[22];
    const float* ln1_b     = (const float*)d_in[23];
    const float* ln2_g     = (const float*)d_in[24];
    const float* ln2_b     = (const float*)d_in[25];
    const float* ln3_g     = (const float*)d_in[26];
    const float* ln3_b     = (const float*)d_in[27];

    float* ws = (float*)d_ws;
    const size_t NLqD = (size_t)NB * LQ * DQ;        // 921600
    float* qk     = ws + 0 * NLqD;
    float* q_proj = ws + 1 * NLqD;
    float* k_proj = ws + 2 * NLqD;
    float* v_proj = ws + 3 * NLqD;
    float* attno  = ws + 4 * NLqD;
    float* sa     = ws + 5 * NLqD;
    float* x1     = ws + 6 * NLqD;
    float* qpe    = ws + 7 * NLqD;
    float* offb   = ws + 8 * NLqD;
    float* dout   = ws + 9 * NLqD;
    float* ca     = ws + 10 * NLqD;
    float* x2     = ws + 11 * NLqD;
    float* ffnout = ws + 12 * NLqD;
    float* awlog  = ws + 13 * NLqD;                  // N*Lq*128
    float* awbuf  = awlog + (size_t)NB * LQ * 128;
    float* ffnh   = ws + 14 * NLqD;                  // slots 14..17
    float* value  = ws + 18 * NLqD;                  // N*Len*256

    // attention partials overlay slots 6..16 (not live during attention)
    float* pO = ws + 6 * NLqD;                       // 10 * NLqD floats
    float* pM = ws + 16 * NLqD;                      // 288000
    float* pL = pM + (size_t)NB * SPLITS * LQ * NHD; // 288000 more

    const int M = NB * LQ;                 // 3600
    const int n4 = (int)(NLqD / 4);

    // 1. qk = queries + q_pos
    hipLaunchKernelGGL(add_kernel, dim3((n4 + 255) / 256), dim3(256), 0, stream,
                       queries, q_pos, qk, n4);
    // 2. q/k/v projections
    gemm64(qk, in_proj_w,            in_proj_b,       q_proj, M, DQ, DQ, 0, stream);
    gemm64(qk, in_proj_w + 256 * DQ, in_proj_b + 256, k_proj, M, DQ, DQ, 0, stream);
    gemm64(queries, in_proj_w + 512 * DQ, in_proj_b + 512, v_proj, M, DQ, DQ, 0, stream);
    // 3. split-K flash attention + combine
    hipLaunchKernelGGL(attn_split_kernel, dim3((LQ + 255) / 256, NHD, NB * SPLITS),
                       dim3(256), 0, stream, q_proj, k_proj, v_proj, pO, pM, pL);
    hipLaunchKernelGGL(attn_combine_kernel, dim3(M), dim3(256), 0, stream, pO, pM, pL, attno);
    // 4. mha out projection
    gemm64(attno, mha_out_w, mha_out_b, sa, M, DQ, DQ, 0, stream);
    // 5. x1 = LN(queries + sa)
    hipLaunchKernelGGL(ln_kernel, dim3(M), dim3(64), 0, stream, queries, sa, ln1_g, ln1_b, x1);
    // 6. qpe = x1 + q_pos
    hipLaunchKernelGGL(add_kernel, dim3((n4 + 255) / 256), dim3(256), 0, stream,
                       x1, q_pos, qpe, n4);
    // 7. value projection over features
    gemm128(features, value_proj_w, value_proj_b, value, NB * LEN_IN, DQ, DKV, 0, stream);
    // 8. sampling offsets
    gemm64(qpe, samp_off_w, samp_off_b, offb, M, DQ, DQ, 0, stream);
    // 9. attention weights + softmax16
    gemm64(qpe, attn_w_w, attn_w_b, awlog, M, 128, DQ, 0, stream);
    {
        const int total = NB * LQ * NHD;
        hipLaunchKernelGGL(softmax16_kernel, dim3((total + 255) / 256), dim3(256), 0, stream,
                           awlog, awbuf, total);
    }
    // 10. deformable sampling
    hipLaunchKernelGGL(deform_kernel, dim3(NB * LQ), dim3(256), 0, stream,
                       value, ref_pts, offb, awbuf, dout);
    // 11. cross-attention out projection
    gemm64(dout, out_proj_w, out_proj_b, ca, M, DQ, DQ, 0, stream);
    // 12. x2 = LN(x1 + ca)
    hipLaunchKernelGGL(ln_kernel, dim3(M), dim3(64), 0, stream, x1, ca, ln2_g, ln2_b, x2);
    // 13. ffn
    gemm64(x2, ffn_w1, ffn_b1, ffnh, M, DFFN, DQ, 1, stream);
    gemm64(ffnh, ffn_w2, ffn_b2, ffnout, M, DQ, DFFN, 0, stream);
    // 14. out = LN(x2 + ffn)
    hipLaunchKernelGGL(ln_kernel, dim3(M), dim3(64), 0, stream, x2, ffnout, ln3_g, ln3_b, (float*)d_out);
}

// Round 6
// 502.458 us; speedup vs baseline: 2.1450x; 1.1189x over previous
//
#include <hip/hip_runtime.h>
#include <cstddef>

// ---------------------------------------------------------------------------
// DeformableTransformerDecoderLayer — round 6 (= round 3 resubmit; 3x infra timeout):
//   * bf16-resident pipeline: weights/features/activations converted to bf16
//   * GEMM = m97 structure (global_load_lds w16, linear LDS, 16x16x32 MFMA)
//   * attn: bf16 K/V, 8-key chunks (no spill), SPLITS=10 x KPS=96
//   * deform: bf16 value gathers, bf16 output
// ---------------------------------------------------------------------------

typedef unsigned short u16;
typedef short  bf16x8 __attribute__((ext_vector_type(8)));
typedef float  f32x4  __attribute__((ext_vector_type(4)));

constexpr int NB=4, LQ=900, DQ=256, DKV=384, DFFN=1024, NHD=8, DH=32, LEN_IN=17821;
constexpr int MQ     = NB*LQ;        // 3600
constexpr int MQ_PAD = 3648;         // 57*64
constexpr int MV     = NB*LEN_IN;    // 71284
constexpr int MV_PAD = 557*128;      // 71296

#define LN_EPS 1e-5f
#define SPLITS 10
#define KPS    96

__device__ inline u16 f2bf(float f) {
    union { float f; unsigned u; } v; v.f = f;
    unsigned u = v.u;
    u += 0x7fffu + ((u >> 16) & 1u);
    return (u16)(u >> 16);
}
__device__ inline float bf2f(u16 h) {
    union { unsigned u; float f; } v; v.u = ((unsigned)h) << 16; return v.f;
}
__device__ inline void gload_lds16(const u16* g, u16* l) {
    __builtin_amdgcn_global_load_lds(
        (const __attribute__((address_space(1))) unsigned*)g,
        (__attribute__((address_space(3))) unsigned*)l, 16, 0, 0);
}

// ---------------- conversion kernels ----------------
// weights (1,048,576 elems) + queries (921,600) -> one bf16 arena
__global__ void convert_misc_kernel(const float* __restrict__ s0, const float* __restrict__ s1,
        const float* __restrict__ s2, const float* __restrict__ s3, const float* __restrict__ s4,
        const float* __restrict__ s5, const float* __restrict__ s6, const float* __restrict__ s7,
        const float* __restrict__ s8, u16* __restrict__ dst) {
    int i4 = blockIdx.x * 256 + threadIdx.x;
    if (i4 >= 492544) return;
    size_t e = (size_t)i4 * 4;
    const float* src; size_t b;
    if      (e < 196608)  { src = s0; b = 0; }
    else if (e < 262144)  { src = s1; b = 196608; }
    else if (e < 360448)  { src = s2; b = 262144; }
    else if (e < 425984)  { src = s3; b = 360448; }
    else if (e < 458752)  { src = s4; b = 425984; }
    else if (e < 524288)  { src = s5; b = 458752; }
    else if (e < 786432)  { src = s6; b = 524288; }
    else if (e < 1048576) { src = s7; b = 786432; }
    else                  { src = s8; b = 1048576; }
    float4 v = *(const float4*)(src + (e - b));
    dst[e] = f2bf(v.x); dst[e+1] = f2bf(v.y); dst[e+2] = f2bf(v.z); dst[e+3] = f2bf(v.w);
}

__global__ void convert_features_kernel(const float* __restrict__ src, u16* __restrict__ dst) {
    size_t i8 = (size_t)blockIdx.x * 256 + threadIdx.x;
    if (i8 >= (size_t)MV * DKV / 8) return;
    const float4 a = ((const float4*)src)[i8 * 2];
    const float4 b = ((const float4*)src)[i8 * 2 + 1];
    u16 h[8] = {f2bf(a.x), f2bf(a.y), f2bf(a.z), f2bf(a.w),
                f2bf(b.x), f2bf(b.y), f2bf(b.z), f2bf(b.w)};
    *(bf16x8*)(dst + i8 * 8) = *(bf16x8*)h;
}

// c_bf = bf16(a + b), 4 elems/thread
__global__ void addbf_kernel(const float* __restrict__ a, const float* __restrict__ b,
                             u16* __restrict__ c, int n4) {
    int i = blockIdx.x * 256 + threadIdx.x;
    if (i >= n4) return;
    float4 va = ((const float4*)a)[i];
    float4 vb = ((const float4*)b)[i];
    u16 h[4] = {f2bf(va.x + vb.x), f2bf(va.y + vb.y), f2bf(va.z + vb.z), f2bf(va.w + vb.w)};
    *(uint2*)(c + (size_t)i * 4) = *(uint2*)h;
}

// ---------------- bf16 MFMA GEMM (m97 structure) ----------------
// C[M][N] = A[M][K] @ W[N][K]^T + bias.  A,W bf16 (padded rows), out f32 or bf16.
template<int BM, int BN, int WM, int WN, bool OBF, bool RELU>
__global__ __launch_bounds__(256) void gemm_bf16(
        const u16* __restrict__ A, const u16* __restrict__ W,
        const float* __restrict__ bias, void* __restrict__ Cout,
        int M, int N, int K) {
    constexpr int BK = 32;
    __shared__ u16 As[BM * BK];
    __shared__ u16 Bs[BN * BK];
    const int bm = blockIdx.y * BM, bn = blockIdx.x * BN;
    const int tid = threadIdx.x, wid = tid >> 6, lane = tid & 63;
    constexpr int NWC = BN / WN;
    const int wr = wid / NWC, wc = wid % NWC;
    constexpr int MR = WM / 16, NR = WN / 16;
    f32x4 acc[MR][NR];
    #pragma unroll
    for (int i = 0; i < MR; ++i)
        #pragma unroll
        for (int j = 0; j < NR; ++j)
            acc[i][j] = (f32x4){0.f, 0.f, 0.f, 0.f};
    const int r16 = lane & 15;
    const int kb  = (lane >> 4) * 8;

    for (int k0 = 0; k0 < K; k0 += BK) {
        #pragma unroll
        for (int i = 0; i < BM / 64; ++i) {
            const int c = i * 256 + tid;
            gload_lds16(A + (size_t)(bm + (c >> 2)) * K + k0 + (c & 3) * 8, &As[c * 8]);
        }
        #pragma unroll
        for (int i = 0; i < BN / 64; ++i) {
            const int c = i * 256 + tid;
            gload_lds16(W + (size_t)(bn + (c >> 2)) * K + k0 + (c & 3) * 8, &Bs[c * 8]);
        }
        __syncthreads();
        bf16x8 af[MR], bfr[NR];
        #pragma unroll
        for (int i = 0; i < MR; ++i)
            af[i] = *(const bf16x8*)&As[(wr * WM + i * 16 + r16) * BK + kb];
        #pragma unroll
        for (int j = 0; j < NR; ++j)
            bfr[j] = *(const bf16x8*)&Bs[(wc * WN + j * 16 + r16) * BK + kb];
        #pragma unroll
        for (int i = 0; i < MR; ++i)
            #pragma unroll
            for (int j = 0; j < NR; ++j)
                acc[i][j] = __builtin_amdgcn_mfma_f32_16x16x32_bf16(af[i], bfr[j], acc[i][j], 0, 0, 0);
        __syncthreads();
    }
    float* Cf = (float*)Cout;
    u16*   Cb = (u16*)Cout;
    #pragma unroll
    for (int i = 0; i < MR; ++i) {
        #pragma unroll
        for (int j = 0; j < NR; ++j) {
            const int col   = bn + wc * WN + j * 16 + r16;
            const int rbase = bm + wr * WM + i * 16 + (lane >> 4) * 4;
            const float bv = bias[col];
            #pragma unroll
            for (int r = 0; r < 4; ++r) {
                const int row = rbase + r;
                if (row < M) {
                    float v = acc[i][j][r] + bv;
                    if (RELU) v = fmaxf(v, 0.f);
                    if (OBF) Cb[(size_t)row * N + col] = f2bf(v);
                    else     Cf[(size_t)row * N + col] = v;
                }
            }
        }
    }
}

// ---------------- split-K flash MHA (bf16 in, bf16 partial out) ----------------
__global__ __launch_bounds__(256, 4) void attn_split_kernel(
        const u16* __restrict__ qk_proj,   // [MQ][512]  (q | k)
        const u16* __restrict__ v_proj,    // [MQ][256]
        u16* __restrict__ pO, float* __restrict__ pM, float* __restrict__ pL) {
    const int n = blockIdx.z / SPLITS, s = blockIdx.z % SPLITS;
    const int h = blockIdx.y;
    const int q = blockIdx.x * 256 + threadIdx.x;
    const int kbegin = s * KPS;
    const int klim = min(KPS, LQ - kbegin);      // 96 or 36
    __shared__ float Ks[32][32];
    __shared__ float Vs[32][32];
    float qv[DH], o[DH];
    float m = -1e30f, l = 0.f;
    const float scale = 0.17677669529663687f;    // 1/sqrt(32)
    if (q < LQ) {
        const u16* qp = qk_proj + (size_t)(n * LQ + q) * 512 + h * 32;
        #pragma unroll
        for (int c8 = 0; c8 < 4; ++c8) {
            bf16x8 v8 = *(const bf16x8*)(qp + c8 * 8);
            #pragma unroll
            for (int j = 0; j < 8; ++j) { qv[c8*8+j] = bf2f((u16)v8[j]) * scale; o[c8*8+j] = 0.f; }
        }
    }
    const int nt = (klim + 31) / 32;
    for (int t = 0; t < nt; ++t) {
        const int kbase = t * 32;
        {   // stage 32 keys of K and V (bf16 -> f32 LDS)
            const int tt  = threadIdx.x;
            const int key = (tt & 127) >> 2;
            const int c8  = (tt & 3) * 8;
            float fv[8];
            if (kbase + key < klim) {
                const int gk = n * LQ + kbegin + kbase + key;
                const u16* src = (tt < 128)
                    ? qk_proj + (size_t)gk * 512 + 256 + h * 32 + c8
                    : v_proj  + (size_t)gk * 256 + h * 32 + c8;
                bf16x8 v8 = *(const bf16x8*)src;
                #pragma unroll
                for (int i = 0; i < 8; ++i) fv[i] = bf2f((u16)v8[i]);
            } else {
                #pragma unroll
                for (int i = 0; i < 8; ++i) fv[i] = 0.f;
            }
            float* dst = (tt < 128) ? &Ks[key][c8] : &Vs[key][c8];
            *(float4*)dst       = make_float4(fv[0], fv[1], fv[2], fv[3]);
            *(float4*)(dst + 4) = make_float4(fv[4], fv[5], fv[6], fv[7]);
        }
        __syncthreads();
        if (q < LQ) {
            #pragma unroll
            for (int kk8 = 0; kk8 < 4; ++kk8) {
                if (kbase + kk8 * 8 < klim) {
                    float s8[8]; float tmax = -1e30f;
                    #pragma unroll
                    for (int j = 0; j < 8; ++j) {
                        const int kk = kk8 * 8 + j;
                        float a2 = 0.f;
                        #pragma unroll
                        for (int d = 0; d < DH; ++d) a2 += qv[d] * Ks[kk][d];
                        s8[j] = (kbase + kk < klim) ? a2 : -1e30f;
                        tmax = fmaxf(tmax, s8[j]);
                    }
                    const float mnew = fmaxf(m, tmax);
                    const float corr = __expf(m - mnew);
                    l *= corr;
                    #pragma unroll
                    for (int d = 0; d < DH; ++d) o[d] *= corr;
                    #pragma unroll
                    for (int j = 0; j < 8; ++j) {
                        const float p = __expf(s8[j] - mnew);
                        l += p;
                        const int kk = kk8 * 8 + j;
                        #pragma unroll
                        for (int d = 0; d < DH; ++d) o[d] += p * Vs[kk][d];
                    }
                    m = mnew;
                }
            }
        }
        __syncthreads();
    }
    if (q < LQ) {
        const size_t idx = ((size_t)((n * SPLITS + s) * LQ + q)) * NHD + h;
        u16* op = pO + idx * 32;
        #pragma unroll
        for (int d = 0; d < DH; ++d) op[d] = f2bf(o[d]);
        pM[idx] = m;
        pL[idx] = l;
    }
}

__global__ __launch_bounds__(256) void attn_combine_kernel(
        const u16* __restrict__ pO, const float* __restrict__ pM,
        const float* __restrict__ pL, u16* __restrict__ attno) {
    const int nq = blockIdx.x;
    const int n = nq / LQ, q = nq % LQ;
    const int h = threadIdx.x >> 5, d = threadIdx.x & 31;
    float ms[SPLITS], ls[SPLITS];
    float m = -1e30f;
    #pragma unroll
    for (int s = 0; s < SPLITS; ++s) {
        const size_t idx = ((size_t)((n * SPLITS + s) * LQ + q)) * NHD + h;
        ms[s] = pM[idx]; ls[s] = pL[idx];
        m = fmaxf(m, ms[s]);
    }
    float l = 0.f, o = 0.f;
    #pragma unroll
    for (int s = 0; s < SPLITS; ++s) {
        const size_t idx = ((size_t)((n * SPLITS + s) * LQ + q)) * NHD + h;
        const float w = __expf(ms[s] - m);
        l += w * ls[s];
        o += w * bf2f(pO[idx * 32 + d]);
    }
    attno[(size_t)nq * 256 + h * 32 + d] = f2bf(o / l);
}

// ---------------- fused residual + LayerNorm (optional bf16 copy) ----------------
template<bool WBF>
__global__ __launch_bounds__(64) void ln_kernel(
        const float* __restrict__ a, const float* __restrict__ b,
        const float* __restrict__ g, const float* __restrict__ beta,
        float* __restrict__ outf, u16* __restrict__ outb) {
    const int row = blockIdx.x;
    const int lane = threadIdx.x;
    const float* ap = &a[(size_t)row * DQ];
    const float* bp = &b[(size_t)row * DQ];
    float x[4];
    float s = 0.f;
    #pragma unroll
    for (int i = 0; i < 4; ++i) { x[i] = ap[lane + i * 64] + bp[lane + i * 64]; s += x[i]; }
    #pragma unroll
    for (int off = 32; off > 0; off >>= 1) s += __shfl_xor(s, off);
    const float mean = s * (1.f / DQ);
    float v = 0.f;
    #pragma unroll
    for (int i = 0; i < 4; ++i) { const float d = x[i] - mean; v += d * d; }
    #pragma unroll
    for (int off = 32; off > 0; off >>= 1) v += __shfl_xor(v, off);
    const float rstd = rsqrtf(v * (1.f / DQ) + LN_EPS);
    #pragma unroll
    for (int i = 0; i < 4; ++i) {
        const int c = lane + i * 64;
        const float y = (x[i] - mean) * rstd * g[c] + beta[c];
        outf[(size_t)row * DQ + c] = y;
        if (WBF) outb[(size_t)row * DQ + c] = f2bf(y);
    }
}

// ---------------- softmax over 16 per (n,q,h) ----------------
__global__ void softmax16_kernel(const float* __restrict__ in, float* __restrict__ out, int total) {
    const int i = blockIdx.x * blockDim.x + threadIdx.x;
    if (i >= total) return;
    const float* p = &in[(size_t)i * 16];
    float mx = -1e30f;
    float e[16];
    #pragma unroll
    for (int j = 0; j < 16; ++j) mx = fmaxf(mx, p[j]);
    float sum = 0.f;
    #pragma unroll
    for (int j = 0; j < 16; ++j) { e[j] = __expf(p[j] - mx); sum += e[j]; }
    const float inv = 1.f / sum;
    #pragma unroll
    for (int j = 0; j < 16; ++j) out[(size_t)i * 16 + j] = e[j] * inv;
}

// ---------------- deformable sampling (bf16 value, bf16 out) ----------------
__global__ __launch_bounds__(256) void deform_kernel(
        const u16* __restrict__ value,       // (N, Len, NH, DH) bf16
        const float* __restrict__ ref_pts,   // (N, Lq, NL, 2)
        const float* __restrict__ off,       // (N, Lq, NH, NL, NP, 2)
        const float* __restrict__ aw,        // (N, Lq, NH, NL*NP)
        u16* __restrict__ out) {             // (N, Lq, NH, DH) bf16
    const int nq = blockIdx.x;
    const int n = nq / LQ, q = nq % LQ;
    const int h = threadIdx.x / DH, d = threadIdx.x % DH;
    const int Hs[4] = {100, 50, 25, 13};
    const int Ws[4] = {134, 67, 34, 17};
    const int LS[4] = {0, 13400, 16750, 17600};
    const float* refp = &ref_pts[((size_t)(n * LQ + q)) * 8];
    const float* offp = &off[((size_t)((n * LQ + q) * NHD + h)) * 32];
    const float* awp  = &aw[((size_t)((n * LQ + q) * NHD + h)) * 16];
    const u16* vb = &value[(size_t)n * LEN_IN * DQ + h * DH + d];
    float acc = 0.f;
    #pragma unroll
    for (int l = 0; l < 4; ++l) {
        const float Wl = (float)Ws[l], Hl = (float)Hs[l];
        const float rx = refp[l * 2 + 0], ry = refp[l * 2 + 1];
        const int Wi = Ws[l], Hi = Hs[l], base = LS[l];
        #pragma unroll
        for (int p = 0; p < 4; ++p) {
            const float ox = offp[(l * 4 + p) * 2 + 0];
            const float oy = offp[(l * 4 + p) * 2 + 1];
            const float gx = (rx + ox / Wl) * Wl - 0.5f;
            const float gy = (ry + oy / Hl) * Hl - 0.5f;
            const float x0f = floorf(gx), y0f = floorf(gy);
            const int x0 = (int)x0f, y0 = (int)y0f;
            const int x1 = x0 + 1, y1 = y0 + 1;
            const float wx1 = gx - x0f, wx0 = 1.f - wx1;
            const float wy1 = gy - y0f, wy0 = 1.f - wy1;
            float sample = 0.f;
            if (x0 >= 0 && x0 < Wi && y0 >= 0 && y0 < Hi)
                sample += wx0 * wy0 * bf2f(vb[(size_t)(base + y0 * Wi + x0) * DQ]);
            if (x1 >= 0 && x1 < Wi && y0 >= 0 && y0 < Hi)
                sample += wx1 * wy0 * bf2f(vb[(size_t)(base + y0 * Wi + x1) * DQ]);
            if (x0 >= 0 && x0 < Wi && y1 >= 0 && y1 < Hi)
                sample += wx0 * wy1 * bf2f(vb[(size_t)(base + y1 * Wi + x0) * DQ]);
            if (x1 >= 0 && x1 < Wi && y1 >= 0 && y1 < Hi)
                sample += wx1 * wy1 * bf2f(vb[(size_t)(base + y1 * Wi + x1) * DQ]);
            acc += awp[l * 4 + p] * sample;
        }
    }
    out[((size_t)(n * LQ + q)) * DQ + h * DH + d] = f2bf(acc);
}

// ---------------------------------------------------------------------------
extern "C" void kernel_launch(void* const* d_in, const int* in_sizes, int n_in,
                              void* d_out, int out_size, void* d_ws, size_t ws_size,
                              hipStream_t stream) {
    const float* queries   = (const float*)d_in[0];
    const float* features  = (const float*)d_in[1];
    const float* ref_pts   = (const float*)d_in[2];
    const float* q_pos     = (const float*)d_in[3];
    const float* in_proj_w = (const float*)d_in[6];
    const float* in_proj_b = (const float*)d_in[7];
    const float* mha_out_w = (const float*)d_in[8];
    const float* mha_out_b = (const float*)d_in[9];
    const float* value_proj_w = (const float*)d_in[10];
    const float* value_proj_b = (const float*)d_in[11];
    const float* samp_off_w = (const float*)d_in[12];
    const float* samp_off_b = (const float*)d_in[13];
    const float* attn_w_w  = (const float*)d_in[14];
    const float* attn_w_b  = (const float*)d_in[15];
    const float* out_proj_w = (const float*)d_in[16];
    const float* out_proj_b = (const float*)d_in[17];
    const float* ffn_w1    = (const float*)d_in[18];
    const float* ffn_b1    = (const float*)d_in[19];
    const float* ffn_w2    = (const float*)d_in[20];
    const float* ffn_b2    = (const float*)d_in[21];
    const float* ln1_g     = (const float*)d_in[22];
    const float* ln1_b     = (const float*)d_in[23];
    const float* ln2_g     = (const float*)d_in[24];
    const float* ln2_b     = (const float*)d_in[25];
    const float* ln3_g     = (const float*)d_in[26];
    const float* ln3_b     = (const float*)d_in[27];

    // ---- workspace carve (bf16 region first, then f32) ----
    u16* u = (u16*)d_ws;
    u16* wbf      = u; u += 1982464;             // weights (1,048,576) + queries_bf (933,888 padded)
    u16* qk_bf    = u; u += (size_t)MQ_PAD * 256;
    u16* qk_proj  = u; u += (size_t)MQ * 512;
    u16* v_proj   = u; u += (size_t)MQ * 256;
    u16* attno_bf = u; u += (size_t)MQ_PAD * 256;
    u16* qpe_bf   = u; u += (size_t)MQ_PAD * 256;
    u16* x2_bf    = u; u += (size_t)MQ_PAD * 256;
    u16* dout_bf  = u; u += (size_t)MQ_PAD * 256;
    u16* ffnh_bf  = u; u += (size_t)MQ_PAD * 1024;
    u16* areg     = u; u += (size_t)MV_PAD * DKV;   // features_bf  (∪ pO)
    u16* value_bf = u; u += (size_t)MV * 256;

    u16* features_bf = areg;
    u16* pO          = areg;   // lives only attn->combine, before featconv

    const u16* wIn    = wbf + 0;
    const u16* wMha   = wbf + 196608;
    const u16* wVal   = wbf + 262144;
    const u16* wSamp  = wbf + 360448;
    const u16* wAttnw = wbf + 425984;
    const u16* wOut   = wbf + 458752;
    const u16* wF1    = wbf + 524288;
    const u16* wF2    = wbf + 786432;
    const u16* queries_bf = wbf + 1048576;

    float* f = (float*)u;
    float* pM    = f; f += 288000;               // 4*10*900*8
    float* pL    = f; f += 288000;
    float* x1    = f; f += (size_t)MQ * 256;
    float* sa    = f; float* x2 = sa; f += (size_t)MQ * 256;     // sa dead before x2 written
    float* offb  = f; float* ca = offb; f += (size_t)MQ * 256;   // offb dead before ca written
    float* awlog = f; float* ffnout = awlog; f += 460800;        // ffnout overlays awlog+awbuf
    float* awbuf = f; f += 460800;

    const int n4 = MQ * 256 / 4;     // 230400

    // 1. convert weights + queries to bf16
    hipLaunchKernelGGL(convert_misc_kernel, dim3(1924), dim3(256), 0, stream,
                       in_proj_w, mha_out_w, value_proj_w, samp_off_w, attn_w_w,
                       out_proj_w, ffn_w1, ffn_w2, queries, wbf);
    // 2. qk_bf = bf16(queries + q_pos)
    hipLaunchKernelGGL(addbf_kernel, dim3((n4 + 255) / 256), dim3(256), 0, stream,
                       queries, q_pos, qk_bf, n4);
    // 3. q,k projection (N=512) and v projection (N=256)
    hipLaunchKernelGGL((gemm_bf16<64,64,32,32,true,false>), dim3(8, 57), dim3(256), 0, stream,
                       qk_bf, wIn, in_proj_b, (void*)qk_proj, MQ, 512, 256);
    hipLaunchKernelGGL((gemm_bf16<64,64,32,32,true,false>), dim3(4, 57), dim3(256), 0, stream,
                       queries_bf, wIn + 512 * 256, in_proj_b + 512, (void*)v_proj, MQ, 256, 256);
    // 4. split-K flash attention + combine
    hipLaunchKernelGGL(attn_split_kernel, dim3(4, NHD, NB * SPLITS), dim3(256), 0, stream,
                       qk_proj, v_proj, pO, pM, pL);
    hipLaunchKernelGGL(attn_combine_kernel, dim3(MQ), dim3(256), 0, stream, pO, pM, pL, attno_bf);
    // 5. mha out projection -> sa (f32)
    hipLaunchKernelGGL((gemm_bf16<64,64,32,32,false,false>), dim3(4, 57), dim3(256), 0, stream,
                       attno_bf, wMha, mha_out_b, (void*)sa, MQ, 256, 256);
    // 6. x1 = LN(queries + sa)
    hipLaunchKernelGGL((ln_kernel<false>), dim3(MQ), dim3(64), 0, stream,
                       queries, sa, ln1_g, ln1_b, x1, (u16*)nullptr);
    // 7. qpe_bf = bf16(x1 + q_pos)
    hipLaunchKernelGGL(addbf_kernel, dim3((n4 + 255) / 256), dim3(256), 0, stream,
                       x1, q_pos, qpe_bf, n4);
    // 8. features -> bf16 (reuses pO space; attention is done)
    hipLaunchKernelGGL(convert_features_kernel, dim3(13366), dim3(256), 0, stream,
                       features, features_bf);
    // 9. value projection -> bf16
    hipLaunchKernelGGL((gemm_bf16<128,128,64,64,true,false>), dim3(2, 557), dim3(256), 0, stream,
                       features_bf, wVal, value_proj_b, (void*)value_bf, MV, 256, DKV);
    // 10. sampling offsets (f32) + attention weights (f32) + softmax16
    hipLaunchKernelGGL((gemm_bf16<64,64,32,32,false,false>), dim3(4, 57), dim3(256), 0, stream,
                       qpe_bf, wSamp, samp_off_b, (void*)offb, MQ, 256, 256);
    hipLaunchKernelGGL((gemm_bf16<64,64,32,32,false,false>), dim3(2, 57), dim3(256), 0, stream,
                       qpe_bf, wAttnw, attn_w_b, (void*)awlog, MQ, 128, 256);
    hipLaunchKernelGGL(softmax16_kernel, dim3((MQ * NHD + 255) / 256), dim3(256), 0, stream,
                       awlog, awbuf, MQ * NHD);
    // 11. deformable sampling -> bf16
    hipLaunchKernelGGL(deform_kernel, dim3(NB * LQ), dim3(256), 0, stream,
                       value_bf, ref_pts, offb, awbuf, dout_bf);
    // 12. cross-attention out projection -> ca (f32)
    hipLaunchKernelGGL((gemm_bf16<64,64,32,32,false,false>), dim3(4, 57), dim3(256), 0, stream,
                       dout_bf, wOut, out_proj_b, (void*)ca, MQ, 256, 256);
    // 13. x2 = LN(x1 + ca), also bf16 copy
    hipLaunchKernelGGL((ln_kernel<true>), dim3(MQ), dim3(64), 0, stream,
                       x1, ca, ln2_g, ln2_b, x2, x2_bf);
    // 14. ffn
    hipLaunchKernelGGL((gemm_bf16<64,64,32,32,true,true>), dim3(16, 57), dim3(256), 0, stream,
                       x2_bf, wF1, ffn_b1, (void*)ffnh_bf, MQ, DFFN, 256);
    hipLaunchKernelGGL((gemm_bf16<64,64,32,32,false,false>), dim3(4, 57), dim3(256), 0, stream,
                       ffnh_bf, wF2, ffn_b2, (void*)ffnout, MQ, 256, DFFN);
    // 15. out = LN(x2 + ffn)
    hipLaunchKernelGGL((ln_kernel<false>), dim3(MQ), dim3(64), 0, stream,
                       x2, ffnout, ln3_g, ln3_b, (float*)d_out, (u16*)nullptr);
}

// Round 7
// 426.083 us; speedup vs baseline: 2.5295x; 1.1792x over previous
//
#include <hip/hip_runtime.h>
#include <cstddef>

// ---------------------------------------------------------------------------
// DeformableTransformerDecoderLayer — round 7:
//   * self-attention -> MFMA flash (S^T = mfma(K,Q), PV via V^T, per-wave P LDS)
//   * v_proj GEMM writes V transposed [n][h][dim][912] for the attn A-operand
//   * everything else unchanged from the passing round-6 kernel
// ---------------------------------------------------------------------------

typedef unsigned short u16;
typedef short  bf16x8 __attribute__((ext_vector_type(8)));
typedef float  f32x4  __attribute__((ext_vector_type(4)));

constexpr int NB=4, LQ=900, DQ=256, DKV=384, DFFN=1024, NHD=8, DH=32, LEN_IN=17821;
constexpr int MQ     = NB*LQ;        // 3600
constexpr int MQ_PAD = 3648;         // 57*64
constexpr int MV     = NB*LEN_IN;    // 71284
constexpr int MV_PAD = 557*128;      // 71296
constexpr int VT_STRIDE = 912;       // token stride of V^T rows (16B aligned)

#define LN_EPS 1e-5f

__device__ inline u16 f2bf(float f) {
    union { float f; unsigned u; } v; v.f = f;
    unsigned u = v.u;
    u += 0x7fffu + ((u >> 16) & 1u);
    return (u16)(u >> 16);
}
__device__ inline float bf2f(u16 h) {
    union { unsigned u; float f; } v; v.u = ((unsigned)h) << 16; return v.f;
}
__device__ inline void gload_lds16(const u16* g, u16* l) {
    __builtin_amdgcn_global_load_lds(
        (const __attribute__((address_space(1))) unsigned*)g,
        (__attribute__((address_space(3))) unsigned*)l, 16, 0, 0);
}

// ---------------- conversion kernels ----------------
__global__ void convert_misc_kernel(const float* __restrict__ s0, const float* __restrict__ s1,
        const float* __restrict__ s2, const float* __restrict__ s3, const float* __restrict__ s4,
        const float* __restrict__ s5, const float* __restrict__ s6, const float* __restrict__ s7,
        const float* __restrict__ s8, u16* __restrict__ dst) {
    int i4 = blockIdx.x * 256 + threadIdx.x;
    if (i4 >= 492544) return;
    size_t e = (size_t)i4 * 4;
    const float* src; size_t b;
    if      (e < 196608)  { src = s0; b = 0; }
    else if (e < 262144)  { src = s1; b = 196608; }
    else if (e < 360448)  { src = s2; b = 262144; }
    else if (e < 425984)  { src = s3; b = 360448; }
    else if (e < 458752)  { src = s4; b = 425984; }
    else if (e < 524288)  { src = s5; b = 458752; }
    else if (e < 786432)  { src = s6; b = 524288; }
    else if (e < 1048576) { src = s7; b = 786432; }
    else                  { src = s8; b = 1048576; }
    float4 v = *(const float4*)(src + (e - b));
    dst[e] = f2bf(v.x); dst[e+1] = f2bf(v.y); dst[e+2] = f2bf(v.z); dst[e+3] = f2bf(v.w);
}

__global__ void convert_features_kernel(const float* __restrict__ src, u16* __restrict__ dst) {
    size_t i8 = (size_t)blockIdx.x * 256 + threadIdx.x;
    if (i8 >= (size_t)MV * DKV / 8) return;
    const float4 a = ((const float4*)src)[i8 * 2];
    const float4 b = ((const float4*)src)[i8 * 2 + 1];
    u16 h[8] = {f2bf(a.x), f2bf(a.y), f2bf(a.z), f2bf(a.w),
                f2bf(b.x), f2bf(b.y), f2bf(b.z), f2bf(b.w)};
    *(bf16x8*)(dst + i8 * 8) = *(bf16x8*)h;
}

__global__ void addbf_kernel(const float* __restrict__ a, const float* __restrict__ b,
                             u16* __restrict__ c, int n4) {
    int i = blockIdx.x * 256 + threadIdx.x;
    if (i >= n4) return;
    float4 va = ((const float4*)a)[i];
    float4 vb = ((const float4*)b)[i];
    u16 h[4] = {f2bf(va.x + vb.x), f2bf(va.y + vb.y), f2bf(va.z + vb.z), f2bf(va.w + vb.w)};
    *(uint2*)(c + (size_t)i * 4) = *(uint2*)h;
}

// ---------------- bf16 MFMA GEMM (m97 structure) ----------------
// OMODE: 0 = f32 row-major, 1 = bf16 row-major, 2 = bf16 V^T layout
template<int BM, int BN, int WM, int WN, int OMODE, bool RELU>
__global__ __launch_bounds__(256) void gemm_bf16(
        const u16* __restrict__ A, const u16* __restrict__ W,
        const float* __restrict__ bias, void* __restrict__ Cout,
        int M, int N, int K) {
    constexpr int BK = 32;
    __shared__ u16 As[BM * BK];
    __shared__ u16 Bs[BN * BK];
    const int bm = blockIdx.y * BM, bn = blockIdx.x * BN;
    const int tid = threadIdx.x, wid = tid >> 6, lane = tid & 63;
    constexpr int NWC = BN / WN;
    const int wr = wid / NWC, wc = wid % NWC;
    constexpr int MR = WM / 16, NR = WN / 16;
    f32x4 acc[MR][NR];
    #pragma unroll
    for (int i = 0; i < MR; ++i)
        #pragma unroll
        for (int j = 0; j < NR; ++j)
            acc[i][j] = (f32x4){0.f, 0.f, 0.f, 0.f};
    const int r16 = lane & 15;
    const int kb  = (lane >> 4) * 8;

    for (int k0 = 0; k0 < K; k0 += BK) {
        #pragma unroll
        for (int i = 0; i < BM / 64; ++i) {
            const int c = i * 256 + tid;
            gload_lds16(A + (size_t)(bm + (c >> 2)) * K + k0 + (c & 3) * 8, &As[c * 8]);
        }
        #pragma unroll
        for (int i = 0; i < BN / 64; ++i) {
            const int c = i * 256 + tid;
            gload_lds16(W + (size_t)(bn + (c >> 2)) * K + k0 + (c & 3) * 8, &Bs[c * 8]);
        }
        __syncthreads();
        bf16x8 af[MR], bfr[NR];
        #pragma unroll
        for (int i = 0; i < MR; ++i)
            af[i] = *(const bf16x8*)&As[(wr * WM + i * 16 + r16) * BK + kb];
        #pragma unroll
        for (int j = 0; j < NR; ++j)
            bfr[j] = *(const bf16x8*)&Bs[(wc * WN + j * 16 + r16) * BK + kb];
        #pragma unroll
        for (int i = 0; i < MR; ++i)
            #pragma unroll
            for (int j = 0; j < NR; ++j)
                acc[i][j] = __builtin_amdgcn_mfma_f32_16x16x32_bf16(af[i], bfr[j], acc[i][j], 0, 0, 0);
        __syncthreads();
    }
    float* Cf = (float*)Cout;
    u16*   Cb = (u16*)Cout;
    #pragma unroll
    for (int i = 0; i < MR; ++i) {
        #pragma unroll
        for (int j = 0; j < NR; ++j) {
            const int col   = bn + wc * WN + j * 16 + r16;
            const int rbase = bm + wr * WM + i * 16 + (lane >> 4) * 4;
            const float bv = bias[col];
            if (OMODE == 2) {
                // V^T write: rows are tokens (4 consecutive, same batch since 900%4==0)
                if (rbase < M) {
                    const int nb_ = rbase / LQ, tok = rbase - nb_ * LQ;
                    u16 hv[4];
                    #pragma unroll
                    for (int r = 0; r < 4; ++r) hv[r] = f2bf(acc[i][j][r] + bv);
                    uint2 pk; pk.x = hv[0] | ((unsigned)hv[1] << 16);
                    pk.y = hv[2] | ((unsigned)hv[3] << 16);
                    *(uint2*)(Cb + ((size_t)((nb_ * NHD + (col >> 5)) * DH + (col & 31))) * VT_STRIDE + tok) = pk;
                }
            } else {
                #pragma unroll
                for (int r = 0; r < 4; ++r) {
                    const int row = rbase + r;
                    if (row < M) {
                        float v = acc[i][j][r] + bv;
                        if (RELU) v = fmaxf(v, 0.f);
                        if (OMODE == 1) Cb[(size_t)row * N + col] = f2bf(v);
                        else            Cf[(size_t)row * N + col] = v;
                    }
                }
            }
        }
    }
}

// ---------------- MFMA flash attention ----------------
// Block: 256 thr = 4 waves, 64 q-rows per block (16/wave), one (n,h).
// S^T = mfma(A=K, B=Q): C col = q (lane&15), row = key ((lane>>4)*4+r).
// PV:  O^T = mfma(A=V^T, B=P^T): C col = q, row = dim.
__global__ __launch_bounds__(256) void attn_mfma_kernel(
        const u16* __restrict__ qk_proj,   // [3600][512]  (q | k)
        const u16* __restrict__ vT,        // [(n*8+h)*32+dim][912]
        u16* __restrict__ attno) {         // [3600][256]
    constexpr int NT = 29;                 // ceil(900/32)
    const int n = blockIdx.z, h = blockIdx.y;
    const int q0 = blockIdx.x * 64;
    const int tid = threadIdx.x, wid = tid >> 6;
    const int lane = tid & 63;
    const int lq = lane & 15, lg = lane >> 4;

    __shared__ u16 Kb[2][32 * 32];
    __shared__ u16 Vb[2][32 * 32];
    __shared__ u16 Pl[4][16 * 40];         // per-wave P^T relay, row stride 40

    const int qg  = q0 + wid * 16 + lq;
    const int qcl = min(qg, LQ - 1);
    // Q fragment (B operand): col=q, k=dim=(lg*8+j)
    const bf16x8 qf = *(const bf16x8*)(qk_proj + ((size_t)(n * LQ + qcl)) * 512 + h * 32 + lg * 8);

    f32x4 acc0 = {0.f, 0.f, 0.f, 0.f};     // O^T dims 0-15
    f32x4 acc1 = {0.f, 0.f, 0.f, 0.f};     // O^T dims 16-31
    float m = -1e30f, l = 0.f;
    const float scale = 0.17677669529663687f;

    const int ks8 = (lg ^ ((lq >> 1) & 3)) * 8;   // swizzled k-slot (bf16 offset)

#define STAGE(buf, kt)                                                            \
    do {                                                                          \
        if (tid < 128) {                                                          \
            const int key = tid >> 2, sl = tid & 3;                               \
            const int slg = sl ^ ((key >> 1) & 3);                                \
            const int tok = min((kt) * 32 + key, LQ - 1);                         \
            gload_lds16(qk_proj + ((size_t)(n * LQ + tok)) * 512 + 256 + h * 32 + slg * 8, \
                        &Kb[buf][tid * 8]);                                       \
        } else {                                                                  \
            const int t2 = tid - 128;                                             \
            const int dim = t2 >> 2, sl = t2 & 3;                                 \
            const int slg = sl ^ ((dim >> 1) & 3);                                \
            gload_lds16(vT + ((size_t)((n * NHD + h) * DH + dim)) * VT_STRIDE + (kt) * 32 + slg * 8, \
                        &Vb[buf][t2 * 8]);                                        \
        }                                                                         \
    } while (0)

    STAGE(0, 0);
    __syncthreads();

    for (int kt = 0; kt < NT; ++kt) {
        const int cur = kt & 1;
        if (kt + 1 < NT) STAGE(cur ^ 1, kt + 1);

        const u16* Kc = Kb[cur];
        const u16* Vc = Vb[cur];

        // ---- S^T: two mfmas (keys 0-15, 16-31) ----
        const bf16x8 kf0 = *(const bf16x8*)(Kc + lq * 32 + ks8);
        const bf16x8 kf1 = *(const bf16x8*)(Kc + (16 + lq) * 32 + ks8);
        f32x4 c0 = {0.f, 0.f, 0.f, 0.f}, c1 = {0.f, 0.f, 0.f, 0.f};
        c0 = __builtin_amdgcn_mfma_f32_16x16x32_bf16(kf0, qf, c0, 0, 0, 0);
        c1 = __builtin_amdgcn_mfma_f32_16x16x32_bf16(kf1, qf, c1, 0, 0, 0);

        // ---- softmax (per q = lane&15; 4 lanes share a q via xor 16/32) ----
        float s[8];
        const int kbase = kt * 32 + lg * 4;
        #pragma unroll
        for (int r = 0; r < 4; ++r) {
            s[r]     = (kbase + r      < LQ) ? c0[r] * scale : -1e30f;
            s[4 + r] = (kbase + 16 + r < LQ) ? c1[r] * scale : -1e30f;
        }
        float tmax = s[0];
        #pragma unroll
        for (int i = 1; i < 8; ++i) tmax = fmaxf(tmax, s[i]);
        tmax = fmaxf(tmax, __shfl_xor(tmax, 16));
        tmax = fmaxf(tmax, __shfl_xor(tmax, 32));
        const float mnew = fmaxf(m, tmax);
        const float corr = __expf(m - mnew);
        l *= corr;
        #pragma unroll
        for (int r = 0; r < 4; ++r) { acc0[r] *= corr; acc1[r] *= corr; }
        float p[8], ps = 0.f;
        #pragma unroll
        for (int i = 0; i < 8; ++i) { p[i] = __expf(s[i] - mnew); ps += p[i]; }
        ps += __shfl_xor(ps, 16);
        ps += __shfl_xor(ps, 32);
        l += ps;
        m = mnew;

        // ---- P -> bf16, relay through per-wave LDS to P^T B-frag layout ----
        u16* Pw = Pl[wid];
        {
            uint2 w0, w1;
            w0.x = f2bf(p[0]) | ((unsigned)f2bf(p[1]) << 16);
            w0.y = f2bf(p[2]) | ((unsigned)f2bf(p[3]) << 16);
            w1.x = f2bf(p[4]) | ((unsigned)f2bf(p[5]) << 16);
            w1.y = f2bf(p[6]) | ((unsigned)f2bf(p[7]) << 16);
            *(uint2*)(Pw + lq * 40 + lg * 4)      = w0;   // keys lg*4..+3
            *(uint2*)(Pw + lq * 40 + 16 + lg * 4) = w1;   // keys 16+lg*4..+3
        }
        asm volatile("s_waitcnt lgkmcnt(0)" ::: "memory");
        __builtin_amdgcn_sched_barrier(0);
        // B-frag: col=q=lq, k=key=lg*8+j
        const bf16x8 pt = *(const bf16x8*)(Pw + lq * 40 + lg * 8);

        // ---- PV: O^T += V^T @ P^T (two dim-halves, k=32 keys) ----
        const bf16x8 vf0 = *(const bf16x8*)(Vc + lq * 32 + ks8);
        const bf16x8 vf1 = *(const bf16x8*)(Vc + (16 + lq) * 32 + ks8);
        acc0 = __builtin_amdgcn_mfma_f32_16x16x32_bf16(vf0, pt, acc0, 0, 0, 0);
        acc1 = __builtin_amdgcn_mfma_f32_16x16x32_bf16(vf1, pt, acc1, 0, 0, 0);

        __syncthreads();   // drains prefetch vmcnt + LDS; next tile ready
    }
#undef STAGE

    if (qg < LQ) {
        const float inv = 1.f / l;
        u16* op = attno + ((size_t)(n * LQ + qg)) * DQ + h * DH;
        uint2 o0, o1;
        o0.x = f2bf(acc0[0] * inv) | ((unsigned)f2bf(acc0[1] * inv) << 16);
        o0.y = f2bf(acc0[2] * inv) | ((unsigned)f2bf(acc0[3] * inv) << 16);
        o1.x = f2bf(acc1[0] * inv) | ((unsigned)f2bf(acc1[1] * inv) << 16);
        o1.y = f2bf(acc1[2] * inv) | ((unsigned)f2bf(acc1[3] * inv) << 16);
        *(uint2*)(op + lg * 4)      = o0;   // dims lg*4..+3
        *(uint2*)(op + 16 + lg * 4) = o1;   // dims 16+lg*4..+3
    }
}

// ---------------- fused residual + LayerNorm (optional bf16 copy) ----------------
template<bool WBF>
__global__ __launch_bounds__(64) void ln_kernel(
        const float* __restrict__ a, const float* __restrict__ b,
        const float* __restrict__ g, const float* __restrict__ beta,
        float* __restrict__ outf, u16* __restrict__ outb) {
    const int row = blockIdx.x;
    const int lane = threadIdx.x;
    const float* ap = &a[(size_t)row * DQ];
    const float* bp = &b[(size_t)row * DQ];
    float x[4];
    float s = 0.f;
    #pragma unroll
    for (int i = 0; i < 4; ++i) { x[i] = ap[lane + i * 64] + bp[lane + i * 64]; s += x[i]; }
    #pragma unroll
    for (int off = 32; off > 0; off >>= 1) s += __shfl_xor(s, off);
    const float mean = s * (1.f / DQ);
    float v = 0.f;
    #pragma unroll
    for (int i = 0; i < 4; ++i) { const float d = x[i] - mean; v += d * d; }
    #pragma unroll
    for (int off = 32; off > 0; off >>= 1) v += __shfl_xor(v, off);
    const float rstd = rsqrtf(v * (1.f / DQ) + LN_EPS);
    #pragma unroll
    for (int i = 0; i < 4; ++i) {
        const int c = lane + i * 64;
        const float y = (x[i] - mean) * rstd * g[c] + beta[c];
        outf[(size_t)row * DQ + c] = y;
        if (WBF) outb[(size_t)row * DQ + c] = f2bf(y);
    }
}

// ---------------- softmax over 16 per (n,q,h) ----------------
__global__ void softmax16_kernel(const float* __restrict__ in, float* __restrict__ out, int total) {
    const int i = blockIdx.x * blockDim.x + threadIdx.x;
    if (i >= total) return;
    const float* p = &in[(size_t)i * 16];
    float mx = -1e30f;
    float e[16];
    #pragma unroll
    for (int j = 0; j < 16; ++j) mx = fmaxf(mx, p[j]);
    float sum = 0.f;
    #pragma unroll
    for (int j = 0; j < 16; ++j) { e[j] = __expf(p[j] - mx); sum += e[j]; }
    const float inv = 1.f / sum;
    #pragma unroll
    for (int j = 0; j < 16; ++j) out[(size_t)i * 16 + j] = e[j] * inv;
}

// ---------------- deformable sampling (bf16 value, bf16 out) ----------------
__global__ __launch_bounds__(256) void deform_kernel(
        const u16* __restrict__ value,       // (N, Len, NH, DH) bf16
        const float* __restrict__ ref_pts,   // (N, Lq, NL, 2)
        const float* __restrict__ off,       // (N, Lq, NH, NL, NP, 2)
        const float* __restrict__ aw,        // (N, Lq, NH, NL*NP)
        u16* __restrict__ out) {             // (N, Lq, NH, DH) bf16
    const int nq = blockIdx.x;
    const int n = nq / LQ, q = nq % LQ;
    const int h = threadIdx.x / DH, d = threadIdx.x % DH;
    const int Hs[4] = {100, 50, 25, 13};
    const int Ws[4] = {134, 67, 34, 17};
    const int LS[4] = {0, 13400, 16750, 17600};
    const float* refp = &ref_pts[((size_t)(n * LQ + q)) * 8];
    const float* offp = &off[((size_t)((n * LQ + q) * NHD + h)) * 32];
    const float* awp  = &aw[((size_t)((n * LQ + q) * NHD + h)) * 16];
    const u16* vb = &value[(size_t)n * LEN_IN * DQ + h * DH + d];
    float acc = 0.f;
    #pragma unroll
    for (int l = 0; l < 4; ++l) {
        const float Wl = (float)Ws[l], Hl = (float)Hs[l];
        const float rx = refp[l * 2 + 0], ry = refp[l * 2 + 1];
        const int Wi = Ws[l], Hi = Hs[l], base = LS[l];
        #pragma unroll
        for (int p = 0; p < 4; ++p) {
            const float ox = offp[(l * 4 + p) * 2 + 0];
            const float oy = offp[(l * 4 + p) * 2 + 1];
            const float gx = (rx + ox / Wl) * Wl - 0.5f;
            const float gy = (ry + oy / Hl) * Hl - 0.5f;
            const float x0f = floorf(gx), y0f = floorf(gy);
            const int x0 = (int)x0f, y0 = (int)y0f;
            const int x1 = x0 + 1, y1 = y0 + 1;
            const float wx1 = gx - x0f, wx0 = 1.f - wx1;
            const float wy1 = gy - y0f, wy0 = 1.f - wy1;
            float sample = 0.f;
            if (x0 >= 0 && x0 < Wi && y0 >= 0 && y0 < Hi)
                sample += wx0 * wy0 * bf2f(vb[(size_t)(base + y0 * Wi + x0) * DQ]);
            if (x1 >= 0 && x1 < Wi && y0 >= 0 && y0 < Hi)
                sample += wx1 * wy0 * bf2f(vb[(size_t)(base + y0 * Wi + x1) * DQ]);
            if (x0 >= 0 && x0 < Wi && y1 >= 0 && y1 < Hi)
                sample += wx0 * wy1 * bf2f(vb[(size_t)(base + y1 * Wi + x0) * DQ]);
            if (x1 >= 0 && x1 < Wi && y1 >= 0 && y1 < Hi)
                sample += wx1 * wy1 * bf2f(vb[(size_t)(base + y1 * Wi + x1) * DQ]);
            acc += awp[l * 4 + p] * sample;
        }
    }
    out[((size_t)(n * LQ + q)) * DQ + h * DH + d] = f2bf(acc);
}

// ---------------------------------------------------------------------------
extern "C" void kernel_launch(void* const* d_in, const int* in_sizes, int n_in,
                              void* d_out, int out_size, void* d_ws, size_t ws_size,
                              hipStream_t stream) {
    const float* queries   = (const float*)d_in[0];
    const float* features  = (const float*)d_in[1];
    const float* ref_pts   = (const float*)d_in[2];
    const float* q_pos     = (const float*)d_in[3];
    const float* in_proj_w = (const float*)d_in[6];
    const float* in_proj_b = (const float*)d_in[7];
    const float* mha_out_w = (const float*)d_in[8];
    const float* mha_out_b = (const float*)d_in[9];
    const float* value_proj_w = (const float*)d_in[10];
    const float* value_proj_b = (const float*)d_in[11];
    const float* samp_off_w = (const float*)d_in[12];
    const float* samp_off_b = (const float*)d_in[13];
    const float* attn_w_w  = (const float*)d_in[14];
    const float* attn_w_b  = (const float*)d_in[15];
    const float* out_proj_w = (const float*)d_in[16];
    const float* out_proj_b = (const float*)d_in[17];
    const float* ffn_w1    = (const float*)d_in[18];
    const float* ffn_b1    = (const float*)d_in[19];
    const float* ffn_w2    = (const float*)d_in[20];
    const float* ffn_b2    = (const float*)d_in[21];
    const float* ln1_g     = (const float*)d_in[22];
    const float* ln1_b     = (const float*)d_in[23];
    const float* ln2_g     = (const float*)d_in[24];
    const float* ln2_b     = (const float*)d_in[25];
    const float* ln3_g     = (const float*)d_in[26];
    const float* ln3_b     = (const float*)d_in[27];

    // ---- workspace carve (bf16 region first, then f32) ----
    u16* u = (u16*)d_ws;
    u16* wbf      = u; u += 1982464;             // weights + queries_bf
    u16* qk_bf    = u; u += (size_t)MQ_PAD * 256;
    u16* qk_proj  = u; u += (size_t)MQ * 512;
    u16* vT       = u; u += (size_t)NB * NHD * DH * VT_STRIDE + 64;  // [n][h][dim][912] + tail pad
    u16* attno_bf = u; u += (size_t)MQ_PAD * 256;
    u16* qpe_bf   = u; u += (size_t)MQ_PAD * 256;
    u16* x2_bf    = u; u += (size_t)MQ_PAD * 256;
    u16* dout_bf  = u; u += (size_t)MQ_PAD * 256;
    u16* ffnh_bf  = u; u += (size_t)MQ_PAD * 1024;
    u16* features_bf = u; u += (size_t)MV_PAD * DKV;
    u16* value_bf = u; u += (size_t)MV * 256;

    const u16* wIn    = wbf + 0;
    const u16* wMha   = wbf + 196608;
    const u16* wVal   = wbf + 262144;
    const u16* wSamp  = wbf + 360448;
    const u16* wAttnw = wbf + 425984;
    const u16* wOut   = wbf + 458752;
    const u16* wF1    = wbf + 524288;
    const u16* wF2    = wbf + 786432;
    const u16* queries_bf = wbf + 1048576;

    float* f = (float*)u;
    float* x1    = f; f += (size_t)MQ * 256;
    float* sa    = f; float* x2 = sa; f += (size_t)MQ * 256;     // sa dead before x2 written
    float* offb  = f; float* ca = offb; f += (size_t)MQ * 256;   // offb dead before ca written
    float* awlog = f; float* ffnout = awlog; f += 460800;        // ffnout overlays awlog+awbuf
    float* awbuf = f; f += 460800;

    const int n4 = MQ * 256 / 4;     // 230400

    // 1. convert weights + queries to bf16
    hipLaunchKernelGGL(convert_misc_kernel, dim3(1924), dim3(256), 0, stream,
                       in_proj_w, mha_out_w, value_proj_w, samp_off_w, attn_w_w,
                       out_proj_w, ffn_w1, ffn_w2, queries, wbf);
    // 2. qk_bf = bf16(queries + q_pos)
    hipLaunchKernelGGL(addbf_kernel, dim3((n4 + 255) / 256), dim3(256), 0, stream,
                       queries, q_pos, qk_bf, n4);
    // 3. q,k projection (N=512); v projection written transposed (V^T)
    hipLaunchKernelGGL((gemm_bf16<64,64,32,32,1,false>), dim3(8, 57), dim3(256), 0, stream,
                       qk_bf, wIn, in_proj_b, (void*)qk_proj, MQ, 512, 256);
    hipLaunchKernelGGL((gemm_bf16<64,64,32,32,2,false>), dim3(4, 57), dim3(256), 0, stream,
                       queries_bf, wIn + 512 * 256, in_proj_b + 512, (void*)vT, MQ, 256, 256);
    // 4. MFMA flash attention -> attno_bf
    hipLaunchKernelGGL(attn_mfma_kernel, dim3(15, NHD, NB), dim3(256), 0, stream,
                       qk_proj, vT, attno_bf);
    // 5. mha out projection -> sa (f32)
    hipLaunchKernelGGL((gemm_bf16<64,64,32,32,0,false>), dim3(4, 57), dim3(256), 0, stream,
                       attno_bf, wMha, mha_out_b, (void*)sa, MQ, 256, 256);
    // 6. x1 = LN(queries + sa)
    hipLaunchKernelGGL((ln_kernel<false>), dim3(MQ), dim3(64), 0, stream,
                       queries, sa, ln1_g, ln1_b, x1, (u16*)nullptr);
    // 7. qpe_bf = bf16(x1 + q_pos)
    hipLaunchKernelGGL(addbf_kernel, dim3((n4 + 255) / 256), dim3(256), 0, stream,
                       x1, q_pos, qpe_bf, n4);
    // 8. features -> bf16
    hipLaunchKernelGGL(convert_features_kernel, dim3(13366), dim3(256), 0, stream,
                       features, features_bf);
    // 9. value projection -> bf16
    hipLaunchKernelGGL((gemm_bf16<128,128,64,64,1,false>), dim3(2, 557), dim3(256), 0, stream,
                       features_bf, wVal, value_proj_b, (void*)value_bf, MV, 256, DKV);
    // 10. sampling offsets (f32) + attention weights (f32) + softmax16
    hipLaunchKernelGGL((gemm_bf16<64,64,32,32,0,false>), dim3(4, 57), dim3(256), 0, stream,
                       qpe_bf, wSamp, samp_off_b, (void*)offb, MQ, 256, 256);
    hipLaunchKernelGGL((gemm_bf16<64,64,32,32,0,false>), dim3(2, 57), dim3(256), 0, stream,
                       qpe_bf, wAttnw, attn_w_b, (void*)awlog, MQ, 128, 256);
    hipLaunchKernelGGL(softmax16_kernel, dim3((MQ * NHD + 255) / 256), dim3(256), 0, stream,
                       awlog, awbuf, MQ * NHD);
    // 11. deformable sampling -> bf16
    hipLaunchKernelGGL(deform_kernel, dim3(NB * LQ), dim3(256), 0, stream,
                       value_bf, ref_pts, offb, awbuf, dout_bf);
    // 12. cross-attention out projection -> ca (f32)
    hipLaunchKernelGGL((gemm_bf16<64,64,32,32,0,false>), dim3(4, 57), dim3(256), 0, stream,
                       dout_bf, wOut, out_proj_b, (void*)ca, MQ, 256, 256);
    // 13. x2 = LN(x1 + ca), also bf16 copy
    hipLaunchKernelGGL((ln_kernel<true>), dim3(MQ), dim3(64), 0, stream,
                       x1, ca, ln2_g, ln2_b, x2, x2_bf);
    // 14. ffn
    hipLaunchKernelGGL((gemm_bf16<64,64,32,32,1,true>), dim3(16, 57), dim3(256), 0, stream,
                       x2_bf, wF1, ffn_b1, (void*)ffnh_bf, MQ, DFFN, 256);
    hipLaunchKernelGGL((gemm_bf16<64,64,32,32,0,false>), dim3(4, 57), dim3(256), 0, stream,
                       ffnh_bf, wF2, ffn_b2, (void*)ffnout, MQ, 256, DFFN);
    // 15. out = LN(x2 + ffn)
    hipLaunchKernelGGL((ln_kernel<false>), dim3(MQ), dim3(64), 0, stream,
                       x2, ffnout, ln3_g, ln3_b, (float*)d_out, (u16*)nullptr);
}

// Round 10
// 401.937 us; speedup vs baseline: 2.6814x; 1.0601x over previous
//
#include <hip/hip_runtime.h>
#include <cstddef>

// ---------------------------------------------------------------------------
// DeformableTransformerDecoderLayer — round 10 (= round 8 resubmit; 2x infra timeout):
//   * gemm_value: reads f32 features directly (reg-convert), BM=64 x BN=256,
//     A read exactly once -> convert_features kernel deleted
//   * samp_off + attn_w merged into one N=384 GEMM (packed weights + bias)
//   * softmax16 folded into deform (reads raw logits)
//   * qpe = bf16(x1 + q_pos) folded into ln1 epilogue
//   * attn/MFMA-flash + rest unchanged from passing round 7
// ---------------------------------------------------------------------------

typedef unsigned short u16;
typedef short  bf16x8 __attribute__((ext_vector_type(8)));
typedef float  f32x4  __attribute__((ext_vector_type(4)));

constexpr int NB=4, LQ=900, DQ=256, DKV=384, DFFN=1024, NHD=8, DH=32, LEN_IN=17821;
constexpr int MQ     = NB*LQ;        // 3600
constexpr int MQ_PAD = 3648;         // 57*64
constexpr int MV     = NB*LEN_IN;    // 71284
constexpr int VT_STRIDE = 912;       // token stride of V^T rows (16B aligned)

#define LN_EPS 1e-5f

__device__ inline u16 f2bf(float f) {
    union { float f; unsigned u; } v; v.f = f;
    unsigned u = v.u;
    u += 0x7fffu + ((u >> 16) & 1u);
    return (u16)(u >> 16);
}
__device__ inline float bf2f(u16 h) {
    union { unsigned u; float f; } v; v.u = ((unsigned)h) << 16; return v.f;
}
__device__ inline void gload_lds16(const u16* g, u16* l) {
    __builtin_amdgcn_global_load_lds(
        (const __attribute__((address_space(1))) unsigned*)g,
        (__attribute__((address_space(3))) unsigned*)l, 16, 0, 0);
}

// ---------------- conversion: weights + queries -> bf16; pack samp/attnw bias
__global__ void convert_misc_kernel(const float* __restrict__ s0, const float* __restrict__ s1,
        const float* __restrict__ s2, const float* __restrict__ s3, const float* __restrict__ s4,
        const float* __restrict__ s5, const float* __restrict__ s6, const float* __restrict__ s7,
        const float* __restrict__ s8, u16* __restrict__ dst,
        const float* __restrict__ sampb, const float* __restrict__ attnb,
        float* __restrict__ pbias) {
    int i4 = blockIdx.x * 256 + threadIdx.x;
    if (i4 >= 492544) {
        const int e2 = (i4 - 492544) * 4;
        if (e2 < 384) {
            float4 v = (e2 < 256) ? *(const float4*)(sampb + e2)
                                  : *(const float4*)(attnb + (e2 - 256));
            *(float4*)(pbias + e2) = v;
        }
        return;
    }
    size_t e = (size_t)i4 * 4;
    const float* src; size_t b;
    if      (e < 196608)  { src = s0; b = 0; }
    else if (e < 262144)  { src = s1; b = 196608; }
    else if (e < 360448)  { src = s2; b = 262144; }
    else if (e < 425984)  { src = s3; b = 360448; }
    else if (e < 458752)  { src = s4; b = 425984; }
    else if (e < 524288)  { src = s5; b = 458752; }
    else if (e < 786432)  { src = s6; b = 524288; }
    else if (e < 1048576) { src = s7; b = 786432; }
    else                  { src = s8; b = 1048576; }
    float4 v = *(const float4*)(src + (e - b));
    dst[e] = f2bf(v.x); dst[e+1] = f2bf(v.y); dst[e+2] = f2bf(v.z); dst[e+3] = f2bf(v.w);
}

__global__ void addbf_kernel(const float* __restrict__ a, const float* __restrict__ b,
                             u16* __restrict__ c, int n4) {
    int i = blockIdx.x * 256 + threadIdx.x;
    if (i >= n4) return;
    float4 va = ((const float4*)a)[i];
    float4 vb = ((const float4*)b)[i];
    u16 h[4] = {f2bf(va.x + vb.x), f2bf(va.y + vb.y), f2bf(va.z + vb.z), f2bf(va.w + vb.w)};
    *(uint2*)(c + (size_t)i * 4) = *(uint2*)h;
}

// ---------------- bf16 MFMA GEMM (m97 structure) ----------------
// OMODE: 0 = f32 row-major, 1 = bf16 row-major, 2 = bf16 V^T layout
template<int BM, int BN, int WM, int WN, int OMODE, bool RELU>
__global__ __launch_bounds__(256) void gemm_bf16(
        const u16* __restrict__ A, const u16* __restrict__ W,
        const float* __restrict__ bias, void* __restrict__ Cout,
        int M, int N, int K) {
    constexpr int BK = 32;
    __shared__ u16 As[BM * BK];
    __shared__ u16 Bs[BN * BK];
    const int bm = blockIdx.y * BM, bn = blockIdx.x * BN;
    const int tid = threadIdx.x, wid = tid >> 6, lane = tid & 63;
    constexpr int NWC = BN / WN;
    const int wr = wid / NWC, wc = wid % NWC;
    constexpr int MR = WM / 16, NR = WN / 16;
    f32x4 acc[MR][NR];
    #pragma unroll
    for (int i = 0; i < MR; ++i)
        #pragma unroll
        for (int j = 0; j < NR; ++j)
            acc[i][j] = (f32x4){0.f, 0.f, 0.f, 0.f};
    const int r16 = lane & 15;
    const int kb  = (lane >> 4) * 8;

    for (int k0 = 0; k0 < K; k0 += BK) {
        #pragma unroll
        for (int i = 0; i < BM / 64; ++i) {
            const int c = i * 256 + tid;
            gload_lds16(A + (size_t)(bm + (c >> 2)) * K + k0 + (c & 3) * 8, &As[c * 8]);
        }
        #pragma unroll
        for (int i = 0; i < BN / 64; ++i) {
            const int c = i * 256 + tid;
            gload_lds16(W + (size_t)(bn + (c >> 2)) * K + k0 + (c & 3) * 8, &Bs[c * 8]);
        }
        __syncthreads();
        bf16x8 af[MR], bfr[NR];
        #pragma unroll
        for (int i = 0; i < MR; ++i)
            af[i] = *(const bf16x8*)&As[(wr * WM + i * 16 + r16) * BK + kb];
        #pragma unroll
        for (int j = 0; j < NR; ++j)
            bfr[j] = *(const bf16x8*)&Bs[(wc * WN + j * 16 + r16) * BK + kb];
        #pragma unroll
        for (int i = 0; i < MR; ++i)
            #pragma unroll
            for (int j = 0; j < NR; ++j)
                acc[i][j] = __builtin_amdgcn_mfma_f32_16x16x32_bf16(af[i], bfr[j], acc[i][j], 0, 0, 0);
        __syncthreads();
    }
    float* Cf = (float*)Cout;
    u16*   Cb = (u16*)Cout;
    #pragma unroll
    for (int i = 0; i < MR; ++i) {
        #pragma unroll
        for (int j = 0; j < NR; ++j) {
            const int col   = bn + wc * WN + j * 16 + r16;
            const int rbase = bm + wr * WM + i * 16 + (lane >> 4) * 4;
            const float bv = bias[col];
            if (OMODE == 2) {
                if (rbase < M) {
                    const int nb_ = rbase / LQ, tok = rbase - nb_ * LQ;
                    u16 hv[4];
                    #pragma unroll
                    for (int r = 0; r < 4; ++r) hv[r] = f2bf(acc[i][j][r] + bv);
                    uint2 pk; pk.x = hv[0] | ((unsigned)hv[1] << 16);
                    pk.y = hv[2] | ((unsigned)hv[3] << 16);
                    *(uint2*)(Cb + ((size_t)((nb_ * NHD + (col >> 5)) * DH + (col & 31))) * VT_STRIDE + tok) = pk;
                }
            } else {
                #pragma unroll
                for (int r = 0; r < 4; ++r) {
                    const int row = rbase + r;
                    if (row < M) {
                        float v = acc[i][j][r] + bv;
                        if (RELU) v = fmaxf(v, 0.f);
                        if (OMODE == 1) Cb[(size_t)row * N + col] = f2bf(v);
                        else            Cf[(size_t)row * N + col] = v;
                    }
                }
            }
        }
    }
}

// ---------------- value projection: f32 A (reg-convert), BM=64 x BN=256 ------
// C[M][256] = bf16( A[M][384] @ W[256][384]^T + bias ).  A read exactly once.
__global__ __launch_bounds__(256) void gemm_value_kernel(
        const float* __restrict__ A, const u16* __restrict__ W,
        const float* __restrict__ bias, u16* __restrict__ C, int M) {
    constexpr int BK = 32, BM = 64, K = DKV;
    __shared__ u16 As[BM * BK];      // 4 KB
    __shared__ u16 Bs[256 * BK];     // 16 KB
    const int bm = blockIdx.x * BM;
    const int tid = threadIdx.x, wid = tid >> 6, lane = tid & 63;
    const int r16 = lane & 15, kb = (lane >> 4) * 8;
    f32x4 acc[4][4];
    #pragma unroll
    for (int i = 0; i < 4; ++i)
        #pragma unroll
        for (int j = 0; j < 4; ++j)
            acc[i][j] = (f32x4){0.f, 0.f, 0.f, 0.f};

    const int arow = tid >> 2, ac8 = (tid & 3) * 8;
    for (int k0 = 0; k0 < K; k0 += BK) {
        // ---- B: 256x32 bf16 via async gload (4 per thread) ----
        #pragma unroll
        for (int i = 0; i < 4; ++i) {
            const int c = i * 256 + tid;                 // 0..1023 segments
            gload_lds16(W + (size_t)(c >> 2) * K + k0 + (c & 3) * 8, &Bs[c * 8]);
        }
        // ---- A: 64x32 f32 -> bf16 in regs -> LDS ----
        {
            float tmp[8] = {0.f, 0.f, 0.f, 0.f, 0.f, 0.f, 0.f, 0.f};
            if (bm + arow < M) {
                *(float4*)tmp       = *(const float4*)(A + (size_t)(bm + arow) * K + k0 + ac8);
                *(float4*)(tmp + 4) = *(const float4*)(A + (size_t)(bm + arow) * K + k0 + ac8 + 4);
            }
            u16 h8[8];
            #pragma unroll
            for (int j = 0; j < 8; ++j) h8[j] = f2bf(tmp[j]);
            *(bf16x8*)&As[arow * 32 + ac8] = *(bf16x8*)h8;
        }
        __syncthreads();
        bf16x8 af[4], bfr[4];
        #pragma unroll
        for (int i = 0; i < 4; ++i)
            af[i] = *(const bf16x8*)&As[(i * 16 + r16) * 32 + kb];
        #pragma unroll
        for (int j = 0; j < 4; ++j)
            bfr[j] = *(const bf16x8*)&Bs[(wid * 64 + j * 16 + r16) * 32 + kb];
        #pragma unroll
        for (int i = 0; i < 4; ++i)
            #pragma unroll
            for (int j = 0; j < 4; ++j)
                acc[i][j] = __builtin_amdgcn_mfma_f32_16x16x32_bf16(af[i], bfr[j], acc[i][j], 0, 0, 0);
        __syncthreads();
    }
    #pragma unroll
    for (int i = 0; i < 4; ++i) {
        #pragma unroll
        for (int j = 0; j < 4; ++j) {
            const int col   = wid * 64 + j * 16 + r16;
            const int rbase = bm + i * 16 + (lane >> 4) * 4;
            const float bv = bias[col];
            #pragma unroll
            for (int r = 0; r < 4; ++r) {
                const int row = rbase + r;
                if (row < M) C[(size_t)row * 256 + col] = f2bf(acc[i][j][r] + bv);
            }
        }
    }
}

// ---------------- MFMA flash attention (unchanged, passing) ----------------
__global__ __launch_bounds__(256) void attn_mfma_kernel(
        const u16* __restrict__ qk_proj,   // [3600][512]  (q | k)
        const u16* __restrict__ vT,        // [(n*8+h)*32+dim][912]
        u16* __restrict__ attno) {         // [3600][256]
    constexpr int NT = 29;
    const int n = blockIdx.z, h = blockIdx.y;
    const int q0 = blockIdx.x * 64;
    const int tid = threadIdx.x, wid = tid >> 6;
    const int lane = tid & 63;
    const int lq = lane & 15, lg = lane >> 4;

    __shared__ u16 Kb[2][32 * 32];
    __shared__ u16 Vb[2][32 * 32];
    __shared__ u16 Pl[4][16 * 40];

    const int qg  = q0 + wid * 16 + lq;
    const int qcl = min(qg, LQ - 1);
    const bf16x8 qf = *(const bf16x8*)(qk_proj + ((size_t)(n * LQ + qcl)) * 512 + h * 32 + lg * 8);

    f32x4 acc0 = {0.f, 0.f, 0.f, 0.f};
    f32x4 acc1 = {0.f, 0.f, 0.f, 0.f};
    float m = -1e30f, l = 0.f;
    const float scale = 0.17677669529663687f;

    const int ks8 = (lg ^ ((lq >> 1) & 3)) * 8;

#define STAGE(buf, kt)                                                            \
    do {                                                                          \
        if (tid < 128) {                                                          \
            const int key = tid >> 2, sl = tid & 3;                               \
            const int slg = sl ^ ((key >> 1) & 3);                                \
            const int tok = min((kt) * 32 + key, LQ - 1);                         \
            gload_lds16(qk_proj + ((size_t)(n * LQ + tok)) * 512 + 256 + h * 32 + slg * 8, \
                        &Kb[buf][tid * 8]);                                       \
        } else {                                                                  \
            const int t2 = tid - 128;                                             \
            const int dim = t2 >> 2, sl = t2 & 3;                                 \
            const int slg = sl ^ ((dim >> 1) & 3);                                \
            gload_lds16(vT + ((size_t)((n * NHD + h) * DH + dim)) * VT_STRIDE + (kt) * 32 + slg * 8, \
                        &Vb[buf][t2 * 8]);                                        \
        }                                                                         \
    } while (0)

    STAGE(0, 0);
    __syncthreads();

    for (int kt = 0; kt < NT; ++kt) {
        const int cur = kt & 1;
        if (kt + 1 < NT) STAGE(cur ^ 1, kt + 1);

        const u16* Kc = Kb[cur];
        const u16* Vc = Vb[cur];

        const bf16x8 kf0 = *(const bf16x8*)(Kc + lq * 32 + ks8);
        const bf16x8 kf1 = *(const bf16x8*)(Kc + (16 + lq) * 32 + ks8);
        f32x4 c0 = {0.f, 0.f, 0.f, 0.f}, c1 = {0.f, 0.f, 0.f, 0.f};
        c0 = __builtin_amdgcn_mfma_f32_16x16x32_bf16(kf0, qf, c0, 0, 0, 0);
        c1 = __builtin_amdgcn_mfma_f32_16x16x32_bf16(kf1, qf, c1, 0, 0, 0);

        float s[8];
        const int kbase = kt * 32 + lg * 4;
        #pragma unroll
        for (int r = 0; r < 4; ++r) {
            s[r]     = (kbase + r      < LQ) ? c0[r] * scale : -1e30f;
            s[4 + r] = (kbase + 16 + r < LQ) ? c1[r] * scale : -1e30f;
        }
        float tmax = s[0];
        #pragma unroll
        for (int i = 1; i < 8; ++i) tmax = fmaxf(tmax, s[i]);
        tmax = fmaxf(tmax, __shfl_xor(tmax, 16));
        tmax = fmaxf(tmax, __shfl_xor(tmax, 32));
        const float mnew = fmaxf(m, tmax);
        const float corr = __expf(m - mnew);
        l *= corr;
        #pragma unroll
        for (int r = 0; r < 4; ++r) { acc0[r] *= corr; acc1[r] *= corr; }
        float p[8], ps = 0.f;
        #pragma unroll
        for (int i = 0; i < 8; ++i) { p[i] = __expf(s[i] - mnew); ps += p[i]; }
        ps += __shfl_xor(ps, 16);
        ps += __shfl_xor(ps, 32);
        l += ps;
        m = mnew;

        u16* Pw = Pl[wid];
        {
            uint2 w0, w1;
            w0.x = f2bf(p[0]) | ((unsigned)f2bf(p[1]) << 16);
            w0.y = f2bf(p[2]) | ((unsigned)f2bf(p[3]) << 16);
            w1.x = f2bf(p[4]) | ((unsigned)f2bf(p[5]) << 16);
            w1.y = f2bf(p[6]) | ((unsigned)f2bf(p[7]) << 16);
            *(uint2*)(Pw + lq * 40 + lg * 4)      = w0;
            *(uint2*)(Pw + lq * 40 + 16 + lg * 4) = w1;
        }
        asm volatile("s_waitcnt lgkmcnt(0)" ::: "memory");
        __builtin_amdgcn_sched_barrier(0);
        const bf16x8 pt = *(const bf16x8*)(Pw + lq * 40 + lg * 8);

        const bf16x8 vf0 = *(const bf16x8*)(Vc + lq * 32 + ks8);
        const bf16x8 vf1 = *(const bf16x8*)(Vc + (16 + lq) * 32 + ks8);
        acc0 = __builtin_amdgcn_mfma_f32_16x16x32_bf16(vf0, pt, acc0, 0, 0, 0);
        acc1 = __builtin_amdgcn_mfma_f32_16x16x32_bf16(vf1, pt, acc1, 0, 0, 0);

        __syncthreads();
    }
#undef STAGE

    if (qg < LQ) {
        const float inv = 1.f / l;
        u16* op = attno + ((size_t)(n * LQ + qg)) * DQ + h * DH;
        uint2 o0, o1;
        o0.x = f2bf(acc0[0] * inv) | ((unsigned)f2bf(acc0[1] * inv) << 16);
        o0.y = f2bf(acc0[2] * inv) | ((unsigned)f2bf(acc0[3] * inv) << 16);
        o1.x = f2bf(acc1[0] * inv) | ((unsigned)f2bf(acc1[1] * inv) << 16);
        o1.y = f2bf(acc1[2] * inv) | ((unsigned)f2bf(acc1[3] * inv) << 16);
        *(uint2*)(op + lg * 4)      = o0;
        *(uint2*)(op + 16 + lg * 4) = o1;
    }
}

// ---------------- fused residual + LayerNorm ----------------
// MODE 0: f32 out only.  MODE 1: + bf16 copy.  MODE 2: + qpe_bf = bf16(y + pos)
template<int MODE>
__global__ __launch_bounds__(64) void ln_kernel(
        const float* __restrict__ a, const float* __restrict__ b,
        const float* __restrict__ g, const float* __restrict__ beta,
        float* __restrict__ outf, u16* __restrict__ outb,
        const float* __restrict__ pos) {
    const int row = blockIdx.x;
    const int lane = threadIdx.x;
    const float* ap = &a[(size_t)row * DQ];
    const float* bp = &b[(size_t)row * DQ];
    float x[4];
    float s = 0.f;
    #pragma unroll
    for (int i = 0; i < 4; ++i) { x[i] = ap[lane + i * 64] + bp[lane + i * 64]; s += x[i]; }
    #pragma unroll
    for (int off = 32; off > 0; off >>= 1) s += __shfl_xor(s, off);
    const float mean = s * (1.f / DQ);
    float v = 0.f;
    #pragma unroll
    for (int i = 0; i < 4; ++i) { const float d = x[i] - mean; v += d * d; }
    #pragma unroll
    for (int off = 32; off > 0; off >>= 1) v += __shfl_xor(v, off);
    const float rstd = rsqrtf(v * (1.f / DQ) + LN_EPS);
    #pragma unroll
    for (int i = 0; i < 4; ++i) {
        const int c = lane + i * 64;
        const float y = (x[i] - mean) * rstd * g[c] + beta[c];
        outf[(size_t)row * DQ + c] = y;
        if (MODE == 1) outb[(size_t)row * DQ + c] = f2bf(y);
        if (MODE == 2) outb[(size_t)row * DQ + c] = f2bf(y + pos[(size_t)row * DQ + c]);
    }
}

// ---------------- deformable sampling + inline softmax16 ----------------
__global__ __launch_bounds__(256) void deform_kernel(
        const u16* __restrict__ value,       // (N, Len, NH, DH) bf16
        const float* __restrict__ ref_pts,   // (N, Lq, NL, 2)
        const float* __restrict__ packed,    // [3600][384] = off(256) | logits(128)
        u16* __restrict__ out) {             // (N, Lq, NH, DH) bf16
    const int nq = blockIdx.x;
    const int n = nq / LQ, q = nq % LQ;
    const int h = threadIdx.x / DH, d = threadIdx.x % DH;
    const int Hs[4] = {100, 50, 25, 13};
    const int Ws[4] = {134, 67, 34, 17};
    const int LS[4] = {0, 13400, 16750, 17600};
    const float* refp = &ref_pts[((size_t)(n * LQ + q)) * 8];
    const float* rowp = packed + (size_t)nq * 384;
    const float* offp = rowp + h * 32;
    const float* lgp  = rowp + 256 + h * 16;
    // inline softmax over the 16 logits of this head
    float w[16];
    float mx = lgp[0];
    #pragma unroll
    for (int j = 1; j < 16; ++j) mx = fmaxf(mx, lgp[j]);
    float sum = 0.f;
    #pragma unroll
    for (int j = 0; j < 16; ++j) { w[j] = __expf(lgp[j] - mx); sum += w[j]; }
    const float winv = 1.f / sum;
    const u16* vb = &value[(size_t)n * LEN_IN * DQ + h * DH + d];
    float acc = 0.f;
    #pragma unroll
    for (int l = 0; l < 4; ++l) {
        const float Wl = (float)Ws[l], Hl = (float)Hs[l];
        const float rx = refp[l * 2 + 0], ry = refp[l * 2 + 1];
        const int Wi = Ws[l], Hi = Hs[l], base = LS[l];
        #pragma unroll
        for (int p = 0; p < 4; ++p) {
            const float ox = offp[(l * 4 + p) * 2 + 0];
            const float oy = offp[(l * 4 + p) * 2 + 1];
            const float gx = (rx + ox / Wl) * Wl - 0.5f;
            const float gy = (ry + oy / Hl) * Hl - 0.5f;
            const float x0f = floorf(gx), y0f = floorf(gy);
            const int x0 = (int)x0f, y0 = (int)y0f;
            const int x1 = x0 + 1, y1 = y0 + 1;
            const float wx1 = gx - x0f, wx0 = 1.f - wx1;
            const float wy1 = gy - y0f, wy0 = 1.f - wy1;
            float sample = 0.f;
            if (x0 >= 0 && x0 < Wi && y0 >= 0 && y0 < Hi)
                sample += wx0 * wy0 * bf2f(vb[(size_t)(base + y0 * Wi + x0) * DQ]);
            if (x1 >= 0 && x1 < Wi && y0 >= 0 && y0 < Hi)
                sample += wx1 * wy0 * bf2f(vb[(size_t)(base + y0 * Wi + x1) * DQ]);
            if (x0 >= 0 && x0 < Wi && y1 >= 0 && y1 < Hi)
                sample += wx0 * wy1 * bf2f(vb[(size_t)(base + y1 * Wi + x0) * DQ]);
            if (x1 >= 0 && x1 < Wi && y1 >= 0 && y1 < Hi)
                sample += wx1 * wy1 * bf2f(vb[(size_t)(base + y1 * Wi + x1) * DQ]);
            acc += w[l * 4 + p] * winv * sample;
        }
    }
    out[((size_t)nq) * DQ + h * DH + d] = f2bf(acc);
}

// ---------------------------------------------------------------------------
extern "C" void kernel_launch(void* const* d_in, const int* in_sizes, int n_in,
                              void* d_out, int out_size, void* d_ws, size_t ws_size,
                              hipStream_t stream) {
    const float* queries   = (const float*)d_in[0];
    const float* features  = (const float*)d_in[1];
    const float* ref_pts   = (const float*)d_in[2];
    const float* q_pos     = (const float*)d_in[3];
    const float* in_proj_w = (const float*)d_in[6];
    const float* in_proj_b = (const float*)d_in[7];
    const float* mha_out_w = (const float*)d_in[8];
    const float* mha_out_b = (const float*)d_in[9];
    const float* value_proj_w = (const float*)d_in[10];
    const float* value_proj_b = (const float*)d_in[11];
    const float* samp_off_w = (const float*)d_in[12];
    const float* samp_off_b = (const float*)d_in[13];
    const float* attn_w_w  = (const float*)d_in[14];
    const float* attn_w_b  = (const float*)d_in[15];
    const float* out_proj_w = (const float*)d_in[16];
    const float* out_proj_b = (const float*)d_in[17];
    const float* ffn_w1    = (const float*)d_in[18];
    const float* ffn_b1    = (const float*)d_in[19];
    const float* ffn_w2    = (const float*)d_in[20];
    const float* ffn_b2    = (const float*)d_in[21];
    const float* ln1_g     = (const float*)d_in[22];
    const float* ln1_b     = (const float*)d_in[23];
    const float* ln2_g     = (const float*)d_in[24];
    const float* ln2_b     = (const float*)d_in[25];
    const float* ln3_g     = (const float*)d_in[26];
    const float* ln3_b     = (const float*)d_in[27];

    // ---- workspace carve (bf16 region first, then f32) ----
    u16* u = (u16*)d_ws;
    u16* wbf      = u; u += 1982464;             // weights + queries_bf
    u16* qk_bf    = u; u += (size_t)MQ_PAD * 256;
    u16* qk_proj  = u; u += (size_t)MQ * 512;
    u16* vT       = u; u += (size_t)NB * NHD * DH * VT_STRIDE + 64;
    u16* attno_bf = u; u += (size_t)MQ_PAD * 256;
    u16* qpe_bf   = u; u += (size_t)MQ_PAD * 256;
    u16* x2_bf    = u; u += (size_t)MQ_PAD * 256;
    u16* dout_bf  = u; u += (size_t)MQ_PAD * 256;
    u16* ffnh_bf  = u; u += (size_t)MQ_PAD * 1024;
    u16* value_bf = u; u += (size_t)MV * 256;

    const u16* wIn    = wbf + 0;
    const u16* wMha   = wbf + 196608;
    const u16* wVal   = wbf + 262144;
    const u16* wSampA = wbf + 360448;            // packed [384][256]: samp(256) + attnw(128)
    const u16* wOut   = wbf + 458752;
    const u16* wF1    = wbf + 524288;
    const u16* wF2    = wbf + 786432;
    const u16* queries_bf = wbf + 1048576;

    float* f = (float*)u;
    float* pbias  = f; f += 384;                 // packed samp+attnw bias
    float* x1     = f; f += (size_t)MQ * 256;
    float* sa     = f; float* x2 = sa; f += (size_t)MQ * 256;    // sa dead before x2
    float* packed = f; float* ca = packed; f += (size_t)MQ * 384; // packed dead before ca
    float* ffnout = f; f += (size_t)MQ * 256;

    const int n4 = MQ * 256 / 4;     // 230400

    // 1. convert weights + queries to bf16; pack samp/attnw bias
    hipLaunchKernelGGL(convert_misc_kernel, dim3(1925), dim3(256), 0, stream,
                       in_proj_w, mha_out_w, value_proj_w, samp_off_w, attn_w_w,
                       out_proj_w, ffn_w1, ffn_w2, queries, wbf,
                       samp_off_b, attn_w_b, pbias);
    // 2. qk_bf = bf16(queries + q_pos)
    hipLaunchKernelGGL(addbf_kernel, dim3((n4 + 255) / 256), dim3(256), 0, stream,
                       queries, q_pos, qk_bf, n4);
    // 3. q,k projection (N=512); v projection written transposed (V^T)
    hipLaunchKernelGGL((gemm_bf16<64,64,32,32,1,false>), dim3(8, 57), dim3(256), 0, stream,
                       qk_bf, wIn, in_proj_b, (void*)qk_proj, MQ, 512, 256);
    hipLaunchKernelGGL((gemm_bf16<64,64,32,32,2,false>), dim3(4, 57), dim3(256), 0, stream,
                       queries_bf, wIn + 512 * 256, in_proj_b + 512, (void*)vT, MQ, 256, 256);
    // 4. MFMA flash attention -> attno_bf
    hipLaunchKernelGGL(attn_mfma_kernel, dim3(15, NHD, NB), dim3(256), 0, stream,
                       qk_proj, vT, attno_bf);
    // 5. mha out projection -> sa (f32)
    hipLaunchKernelGGL((gemm_bf16<64,64,32,32,0,false>), dim3(4, 57), dim3(256), 0, stream,
                       attno_bf, wMha, mha_out_b, (void*)sa, MQ, 256, 256);
    // 6. x1 = LN(queries + sa); qpe_bf = bf16(x1 + q_pos) fused
    hipLaunchKernelGGL((ln_kernel<2>), dim3(MQ), dim3(64), 0, stream,
                       queries, sa, ln1_g, ln1_b, x1, qpe_bf, q_pos);
    // 7. value projection: f32 features -> bf16 value (A read once)
    hipLaunchKernelGGL(gemm_value_kernel, dim3((MV + 63) / 64), dim3(256), 0, stream,
                       features, wVal, value_proj_b, value_bf, MV);
    // 8. merged sampling-offset + attention-weight GEMM (N=384, f32 packed out)
    hipLaunchKernelGGL((gemm_bf16<64,64,32,32,0,false>), dim3(6, 57), dim3(256), 0, stream,
                       qpe_bf, wSampA, pbias, (void*)packed, MQ, 384, 256);
    // 9. deformable sampling (softmax inline) -> bf16
    hipLaunchKernelGGL(deform_kernel, dim3(NB * LQ), dim3(256), 0, stream,
                       value_bf, ref_pts, packed, dout_bf);
    // 10. cross-attention out projection -> ca (f32)
    hipLaunchKernelGGL((gemm_bf16<64,64,32,32,0,false>), dim3(4, 57), dim3(256), 0, stream,
                       dout_bf, wOut, out_proj_b, (void*)ca, MQ, 256, 256);
    // 11. x2 = LN(x1 + ca), also bf16 copy
    hipLaunchKernelGGL((ln_kernel<1>), dim3(MQ), dim3(64), 0, stream,
                       x1, ca, ln2_g, ln2_b, x2, x2_bf, (const float*)nullptr);
    // 12. ffn
    hipLaunchKernelGGL((gemm_bf16<64,64,32,32,1,true>), dim3(16, 57), dim3(256), 0, stream,
                       x2_bf, wF1, ffn_b1, (void*)ffnh_bf, MQ, DFFN, 256);
    hipLaunchKernelGGL((gemm_bf16<64,64,32,32,0,false>), dim3(4, 57), dim3(256), 0, stream,
                       ffnh_bf, wF2, ffn_b2, (void*)ffnout, MQ, 256, DFFN);
    // 13. out = LN(x2 + ffn)
    hipLaunchKernelGGL((ln_kernel<0>), dim3(MQ), dim3(64), 0, stream,
                       x2, ffnout, ln3_g, ln3_b, (float*)d_out, (u16*)nullptr, (const float*)nullptr);
}